// Round 12
// baseline (461.144 us; speedup 1.0000x reference)
//
#include <hip/hip_runtime.h>

#define D_MODEL   2048
#define D_INNER   4096
#define HEADDIM   64
#define NHEADS    64
#define D_STATE   128
#define CHUNK     256
#define CONV_DIM  4352
#define D_IN_PROJ 8512
#define BATCH     2
#define SEQ       2048
#define NCHUNK    8
#define NROWS     4096
#define EPSV      1e-5f
#define CG        (CONV_DIM / 8)   // 544

typedef __attribute__((ext_vector_type(8))) short bf16x8;
typedef __attribute__((ext_vector_type(8))) unsigned short u16x8;
typedef __attribute__((ext_vector_type(4))) float f32x4;

#define AS1 __attribute__((address_space(1)))
#define AS3 __attribute__((address_space(3)))

#define BAR() do { asm volatile("" ::: "memory"); __builtin_amdgcn_s_barrier(); asm volatile("" ::: "memory"); } while (0)

__device__ __forceinline__ unsigned short f2bf(float f) {
  unsigned int x = __float_as_uint(f);
  unsigned int r = (x + 0x7fffu + ((x >> 16) & 1u)) >> 16;
  return (unsigned short)r;
}
__device__ __forceinline__ float bf2f(unsigned short u) {
  return __uint_as_float((unsigned int)u << 16);
}

__global__ void k_sentinel(float* out) { if (threadIdx.x == 0) out[0] = 1.0e6f; }

// ---------------- fused prep: usplit | W_in convert | wpack | conv pack ----------------
__global__ void k_prep(const float* __restrict__ u, unsigned short* __restrict__ uhi, unsigned short* __restrict__ ulo,
                       const float* __restrict__ W, unsigned short* __restrict__ winb, unsigned short* __restrict__ whl,
                       const float* __restrict__ cw, const float* __restrict__ cb,
                       unsigned short* __restrict__ cwT, unsigned short* __restrict__ cbT) {
  const int b = blockIdx.x;
  const int t = threadIdx.x;
  if (b < 2048) {
    const long n4 = (long)NROWS * D_MODEL / 4;
    for (long i = (long)b * 256 + t; i < n4; i += 2048L * 256) {
      float4 v = ((const float4*)u)[i];
      ushort4 h, l;
      h.x = f2bf(v.x); l.x = f2bf(v.x - bf2f(h.x));
      h.y = f2bf(v.y); l.y = f2bf(v.y - bf2f(h.y));
      h.z = f2bf(v.z); l.z = f2bf(v.z - bf2f(h.z));
      h.w = f2bf(v.w); l.w = f2bf(v.w - bf2f(h.w));
      ((ushort4*)uhi)[i] = h;
      ((ushort4*)ulo)[i] = l;
    }
  } else if (b < 6144) {
    const long n4 = (long)D_IN_PROJ * D_MODEL / 4;
    for (long i = (long)(b - 2048) * 256 + t; i < n4; i += 4096L * 256) {
      float4 v = ((const float4*)W)[i];
      ushort4 o = make_ushort4(f2bf(v.x), f2bf(v.y), f2bf(v.z), f2bf(v.w));
      ((ushort4*)winb)[i] = o;
    }
  } else if (b < 6656) {
    long i = (long)(b - 6144) * 256 + t;
    float v = W[(size_t)8448 * D_MODEL + i];
    unsigned short h = f2bf(v);
    whl[i] = h;
    whl[(size_t)64 * D_MODEL + i] = f2bf(v - bf2f(h));
  } else {
    int i = (b - 6656) * 256 + t;
    if (i < CONV_DIM) {
#pragma unroll
      for (int w = 0; w < 4; ++w) cwT[w * CONV_DIM + i] = f2bf(cw[i * 4 + w]);
      cbT[i] = f2bf(cb[i]);
    }
  }
}

// ---------------- W_out convert ----------------
__global__ void k_f32_to_bf16_v4(const float* __restrict__ in, unsigned short* __restrict__ out, long n4) {
  long i = (long)blockIdx.x * blockDim.x + threadIdx.x;
  long stride = (long)gridDim.x * blockDim.x;
  for (; i < n4; i += stride) {
    float4 v = ((const float4*)in)[i];
    ushort4 o = make_ushort4(f2bf(v.x), f2bf(v.y), f2bf(v.z), f2bf(v.w));
    ((ushort4*)out)[i] = o;
  }
}

// ---- dt split-bf16 MFMA, SPLIT-K=4 -> PD[ks][bh][l] (f32) ----
__global__ __launch_bounds__(256, 2) void k_dtm(const unsigned short* __restrict__ uhi,
                                                const unsigned short* __restrict__ ulo,
                                                const unsigned short* __restrict__ whl,
                                                float* __restrict__ PD) {
  __shared__ __align__(16) short lds[2][256 * 64];
  const int t = threadIdx.x;
  const int lane = t & 63;
  const int w = t >> 6;
  const int ks = (int)blockIdx.x & 3;
  const int m0 = ((int)blockIdx.x >> 2) * 64;
  const int kbase = ks * 512;

  f32x4 acc1[8], acc2[4];
#pragma unroll
  for (int j = 0; j < 8; ++j) { f32x4 z = {0.f, 0.f, 0.f, 0.f}; acc1[j] = z; }
#pragma unroll
  for (int j = 0; j < 4; ++j) { f32x4 z = {0.f, 0.f, 0.f, 0.f}; acc2[j] = z; }

  const int srow = t >> 3;
  const int schunk = (t & 7) ^ (srow & 7);
  const unsigned short* gU = uhi + (size_t)(m0 + srow) * D_MODEL + kbase + schunk * 8;
  const unsigned short* gL = ulo + (size_t)(m0 + srow) * D_MODEL + kbase + schunk * 8;
  const unsigned short* gW = whl + (size_t)srow * D_MODEL + kbase + schunk * 8;

  auto STAGE = [&](int buf, int kt) {
    char* d = (char*)&lds[buf][0] + t * 16;
#pragma unroll
    for (int ii = 0; ii < 2; ++ii)
      __builtin_amdgcn_global_load_lds((const AS1 void*)(gU + (size_t)ii * 32 * D_MODEL + (size_t)kt * 64),
                                       (AS3 void*)(d + ii * 4096), 16, 0, 0);
#pragma unroll
    for (int ii = 0; ii < 2; ++ii)
      __builtin_amdgcn_global_load_lds((const AS1 void*)(gL + (size_t)ii * 32 * D_MODEL + (size_t)kt * 64),
                                       (AS3 void*)(d + 8192 + ii * 4096), 16, 0, 0);
#pragma unroll
    for (int ii = 0; ii < 4; ++ii)
      __builtin_amdgcn_global_load_lds((const AS1 void*)(gW + (size_t)ii * 32 * D_MODEL + (size_t)kt * 64),
                                       (AS3 void*)(d + 16384 + ii * 4096), 16, 0, 0);
  };

  STAGE(0, 0);

  const int NT = 512 / 64;
  const int ar = w * 16 + (lane & 15);
  const int kof = (lane >> 4) * 8;
  const int rsw = (lane & 7) * 8;
  int cur = 0;
  for (int kt = 0; kt < NT; ++kt) {
    if (kt + 1 < NT) {
      STAGE(cur ^ 1, kt + 1);
      asm volatile("s_waitcnt vmcnt(8)" ::: "memory");
    } else {
      asm volatile("s_waitcnt vmcnt(0)" ::: "memory");
    }
    __builtin_amdgcn_s_barrier();
    asm volatile("" ::: "memory");
    const short* L = &lds[cur][0];
#pragma unroll
    for (int kk = 0; kk < 2; ++kk) {
      const int off = (kk * 32 + kof) ^ rsw;
      bf16x8 ah = *(const bf16x8*)(L + ar * 64 + off);
      bf16x8 al = *(const bf16x8*)(L + (64 + ar) * 64 + off);
#pragma unroll
      for (int j = 0; j < 8; ++j) {
        bf16x8 bj = *(const bf16x8*)(L + (128 + j * 16 + (lane & 15)) * 64 + off);
        acc1[j] = __builtin_amdgcn_mfma_f32_16x16x32_bf16(ah, bj, acc1[j], 0, 0, 0);
        if (j < 4) acc2[j] = __builtin_amdgcn_mfma_f32_16x16x32_bf16(al, bj, acc2[j], 0, 0, 0);
      }
    }
    asm volatile("" ::: "memory");
    __builtin_amdgcn_s_barrier();
    asm volatile("" ::: "memory");
    cur ^= 1;
  }

  const int crow = (lane >> 4) * 4;
  float* P = PD + (size_t)ks * BATCH * NHEADS * SEQ;
#pragma unroll
  for (int j = 0; j < 4; ++j) {
    int h = j * 16 + (lane & 15);
#pragma unroll
    for (int r = 0; r < 4; ++r) {
      int row = m0 + w * 16 + crow + r;
      float v = acc1[j][r] + acc1[j + 4][r] + acc2[j][r];
      P[(size_t)((row >> 11) * NHEADS + h) * SEQ + (row & 2047)] = v;
    }
  }
}

// ---- dt reduce + softplus -> dtt; fused per-chunk cumsum -> acum ----
__global__ __launch_bounds__(256) void k_dtred(const float* __restrict__ PD, const float* __restrict__ dt_bias,
                                               const float* __restrict__ A_log,
                                               float* __restrict__ dt_t, float* __restrict__ A_cum) {
  const int bh = blockIdx.x;
  const int h = bh & 63;
  const int t = threadIdx.x;
  const float bias = dt_bias[h];
  const float A = -__expf(A_log[h]);
  const size_t base = (size_t)bh * SEQ;
  const size_t pstride = (size_t)BATCH * NHEADS * SEQ;
  __shared__ float s[256];
  for (int c = 0; c < NCHUNK; ++c) {
    int l = c * CHUNK + t;
    float v = PD[base + l] + PD[pstride + base + l] + PD[2 * pstride + base + l] + PD[3 * pstride + base + l] + bias;
    float dtv = (v > 20.f) ? v : log1pf(expf(v));
    dt_t[base + l] = dtv;
    s[t] = dtv * A;
    __syncthreads();
    for (int off = 1; off < 256; off <<= 1) {
      float x = (t >= off) ? s[t - off] : 0.f;
      __syncthreads();
      s[t] += x;
      __syncthreads();
    }
    A_cum[((size_t)bh * NCHUNK + c) * CHUNK + t] = s[t];
    __syncthreads();
  }
}

// ---- 256x256 BK=64 8-phase GEMM (T2+T3+T4+T5), grouped-raster XCD swizzle ----
__global__ __launch_bounds__(512, 2) void k_gemm8p(const unsigned short* __restrict__ A,
                                                   const unsigned short* __restrict__ B,
                                                   unsigned short* __restrict__ C, int M, int N, int K) {
  __shared__ __align__(16) short lds[2][32768];
  const int t = threadIdx.x;
  const int lane = t & 63;
  const int wid = t >> 6;
  const int wr = wid >> 2;
  const int wc = wid & 3;
  const int ntx = N / 256;
  const int nwg = (int)gridDim.x;
  const int bid = (int)blockIdx.x;
  const int swz = (bid & 7) * (nwg >> 3) + (bid >> 3);
  const int grp = ntx << 3;
  const int gid = swz / grp;
  const int rem = swz - gid * grp;
  const int m0 = ((gid << 3) + (rem & 7)) * 256;
  const int n0 = (rem >> 3) * 256;

  f32x4 acc[8][4];
#pragma unroll
  for (int i = 0; i < 8; ++i)
#pragma unroll
    for (int j = 0; j < 4; ++j) { f32x4 z = {0.f, 0.f, 0.f, 0.f}; acc[i][j] = z; }

  const int srow = t >> 3;
  const int schunk = (t & 7) ^ (srow & 7);
  const unsigned short* gA = A + (size_t)(m0 + srow) * K + schunk * 8;
  const unsigned short* gB = B + (size_t)(n0 + srow) * K + schunk * 8;

  auto STAGE_HALF = [&](int buf, int kt, int which) {
    const unsigned short* g = (which < 2 ? gA : gB) + (size_t)(which & 1) * 128 * K + (size_t)kt * 64;
    char* d = (char*)lds + buf * 65536 + which * 16384 + t * 16;
    __builtin_amdgcn_global_load_lds((const AS1 void*)g, (AS3 void*)d, 16, 0, 0);
    __builtin_amdgcn_global_load_lds((const AS1 void*)(g + (size_t)64 * K), (AS3 void*)(d + 8192), 16, 0, 0);
  };

  const int NT = K / 64;
  STAGE_HALF(0, 0, 0); STAGE_HALF(0, 0, 1); STAGE_HALF(0, 0, 2); STAGE_HALF(0, 0, 3);
  STAGE_HALF(1, 1, 2); STAGE_HALF(1, 1, 0); STAGE_HALF(1, 1, 1);
  asm volatile("s_waitcnt vmcnt(6)" ::: "memory");
  BAR();

  const int ar = wr * 128 + (lane & 15);
  const int br = wc * 64 + (lane & 15);
  const int kof = (lane >> 4) * 8;
  const int rsw = (lane & 7) * 8;

  for (int kt = 0; kt < NT; ++kt) {
    const int buf = kt & 1;
    const short* As = &lds[buf][0];
    const short* Bs = &lds[buf][16384];
    const bool s1 = (kt + 1 < NT);
    const bool s2 = (kt + 2 < NT);
    bf16x8 aLo[4][2], aHi[4][2], bLo[2][2], bHi[2][2];

#pragma unroll
    for (int i = 0; i < 4; ++i)
#pragma unroll
      for (int k = 0; k < 2; ++k) aLo[i][k] = *(const bf16x8*)(As + (ar + i * 16) * 64 + ((k * 32 + kof) ^ rsw));
#pragma unroll
    for (int j = 0; j < 2; ++j)
#pragma unroll
      for (int k = 0; k < 2; ++k) bLo[j][k] = *(const bf16x8*)(Bs + (br + j * 16) * 64 + ((k * 32 + kof) ^ rsw));
    if (s1) STAGE_HALF(buf ^ 1, kt + 1, 3);
    BAR();
    __builtin_amdgcn_s_setprio(1);
#pragma unroll
    for (int k = 0; k < 2; ++k)
#pragma unroll
      for (int i = 0; i < 4; ++i)
#pragma unroll
        for (int j = 0; j < 2; ++j)
          acc[i][j] = __builtin_amdgcn_mfma_f32_16x16x32_bf16(aLo[i][k], bLo[j][k], acc[i][j], 0, 0, 0);
    __builtin_amdgcn_s_setprio(0);
    BAR();

#pragma unroll
    for (int j = 0; j < 2; ++j)
#pragma unroll
      for (int k = 0; k < 2; ++k) bHi[j][k] = *(const bf16x8*)(Bs + (br + (j + 2) * 16) * 64 + ((k * 32 + kof) ^ rsw));
    BAR();
    __builtin_amdgcn_s_setprio(1);
#pragma unroll
    for (int k = 0; k < 2; ++k)
#pragma unroll
      for (int i = 0; i < 4; ++i)
#pragma unroll
        for (int j = 0; j < 2; ++j)
          acc[i][j + 2] = __builtin_amdgcn_mfma_f32_16x16x32_bf16(aLo[i][k], bHi[j][k], acc[i][j + 2], 0, 0, 0);
    __builtin_amdgcn_s_setprio(0);
    BAR();

#pragma unroll
    for (int i = 0; i < 4; ++i)
#pragma unroll
      for (int k = 0; k < 2; ++k) aHi[i][k] = *(const bf16x8*)(As + (ar + (i + 4) * 16) * 64 + ((k * 32 + kof) ^ rsw));
    if (s2) STAGE_HALF(buf, kt + 2, 2);
    BAR();
    __builtin_amdgcn_s_setprio(1);
#pragma unroll
    for (int k = 0; k < 2; ++k)
#pragma unroll
      for (int i = 0; i < 4; ++i)
#pragma unroll
        for (int j = 0; j < 2; ++j)
          acc[i + 4][j] = __builtin_amdgcn_mfma_f32_16x16x32_bf16(aHi[i][k], bLo[j][k], acc[i + 4][j], 0, 0, 0);
    __builtin_amdgcn_s_setprio(0);
    BAR();

    if (s2) { STAGE_HALF(buf, kt + 2, 0); STAGE_HALF(buf, kt + 2, 1); }
    if (s2) { asm volatile("s_waitcnt vmcnt(6)" ::: "memory"); }
    else    { asm volatile("s_waitcnt vmcnt(0)" ::: "memory"); }
    BAR();
    __builtin_amdgcn_s_setprio(1);
#pragma unroll
    for (int k = 0; k < 2; ++k)
#pragma unroll
      for (int i = 0; i < 4; ++i)
#pragma unroll
        for (int j = 0; j < 2; ++j)
          acc[i + 4][j + 2] = __builtin_amdgcn_mfma_f32_16x16x32_bf16(aHi[i][k], bHi[j][k], acc[i + 4][j + 2], 0, 0, 0);
    __builtin_amdgcn_s_setprio(0);
    BAR();
  }

  const int crow = (lane >> 4) * 4;
  const int ccol = lane & 15;
#pragma unroll
  for (int i = 0; i < 8; ++i)
#pragma unroll
    for (int j = 0; j < 4; ++j) {
      size_t base = (size_t)(m0 + wr * 128 + i * 16 + crow) * N + (n0 + wc * 64 + j * 16 + ccol);
#pragma unroll
      for (int r = 0; r < 4; ++r) C[base + (size_t)r * N] = f2bf(acc[i][j][r]);
    }
}

// ---- 128x128 BK=32 3-stage pipelined GEMM, GM=4 grouped raster, 3 blocks/CU ----
template <int BF16OUT>
__global__ __launch_bounds__(256, 3) void k_gemm128(const unsigned short* __restrict__ A,
                                                    const unsigned short* __restrict__ B,
                                                    void* __restrict__ Cv, int M, int N, int K) {
  __shared__ __align__(16) short lds[3][8192];   // per buf: A [128][32] shorts 0..4095, B 4096..8191
  const int t = threadIdx.x;
  const int lane = t & 63;
  const int wid = t >> 6;
  const int wr = wid >> 1;
  const int wc = wid & 1;
  const int ntx = N / 128;
  const int nwg = (int)gridDim.x;
  const int bid = (int)blockIdx.x;
  const int swz = (bid & 7) * (nwg >> 3) + (bid >> 3);
  const int grp = ntx << 2;            // GM=4; requires nwg % grp == 0
  const int gid = swz / grp;
  const int rem = swz - gid * grp;
  const int m0 = ((gid << 2) + (rem & 3)) * 128;
  const int n0 = (rem >> 2) * 128;

  f32x4 acc[4][4];
#pragma unroll
  for (int i = 0; i < 4; ++i)
#pragma unroll
    for (int j = 0; j < 4; ++j) { f32x4 z = {0.f, 0.f, 0.f, 0.f}; acc[i][j] = z; }

  // staging: thread t -> row (t>>2) in each 64-row group, 16B chunk ((t&3) ^ (row&3))
  const int srow = t >> 2;             // 0..63
  const int schunk = (t & 3) ^ (srow & 3);
  const unsigned short* gA = A + (size_t)(m0 + srow) * K + schunk * 8;
  const unsigned short* gB = B + (size_t)(n0 + srow) * K + schunk * 8;

  auto STAGE = [&](int buf, int kt) {  // 4 loads/thread
    char* d = (char*)lds + buf * 16384 + t * 16;
#pragma unroll
    for (int ii = 0; ii < 2; ++ii)
      __builtin_amdgcn_global_load_lds((const AS1 void*)(gA + (size_t)ii * 64 * K + (size_t)kt * 32),
                                       (AS3 void*)(d + ii * 4096), 16, 0, 0);
#pragma unroll
    for (int ii = 0; ii < 2; ++ii)
      __builtin_amdgcn_global_load_lds((const AS1 void*)(gB + (size_t)ii * 64 * K + (size_t)kt * 32),
                                       (AS3 void*)(d + 8192 + ii * 4096), 16, 0, 0);
  };

  const int NT = K / 32;
  STAGE(0, 0); STAGE(1, 1); STAGE(2, 2);

  const int ar = wr * 64 + (lane & 15);
  const int br = wc * 64 + (lane & 15);
  const int chnk = lane >> 4;          // wanted 16B chunk (0..3)
  for (int kt = 0; kt < NT; ++kt) {
    const int ahead = NT - 1 - kt;
    if (ahead >= 2)      { asm volatile("s_waitcnt vmcnt(8)" ::: "memory"); }
    else if (ahead == 1) { asm volatile("s_waitcnt vmcnt(4)" ::: "memory"); }
    else                 { asm volatile("s_waitcnt vmcnt(0)" ::: "memory"); }
    __builtin_amdgcn_s_barrier();
    asm volatile("" ::: "memory");
    const int buf = kt % 3;
    const short* As = &lds[buf][0];
    const short* Bs = &lds[buf][4096];
    bf16x8 bfr[4];
#pragma unroll
    for (int j = 0; j < 4; ++j) {
      int row = br + j * 16;
      bfr[j] = *(const bf16x8*)(Bs + row * 32 + ((chnk ^ (row & 3)) * 8));
    }
#pragma unroll
    for (int i = 0; i < 4; ++i) {
      int row = ar + i * 16;
      bf16x8 af = *(const bf16x8*)(As + row * 32 + ((chnk ^ (row & 3)) * 8));
#pragma unroll
      for (int j = 0; j < 4; ++j)
        acc[i][j] = __builtin_amdgcn_mfma_f32_16x16x32_bf16(af, bfr[j], acc[i][j], 0, 0, 0);
    }
    asm volatile("" ::: "memory");
    __builtin_amdgcn_s_barrier();
    asm volatile("" ::: "memory");
    if (kt + 3 < NT) STAGE(buf, kt + 3);
  }

  const int crow = (lane >> 4) * 4;
  const int ccol = lane & 15;
#pragma unroll
  for (int i = 0; i < 4; ++i)
#pragma unroll
    for (int j = 0; j < 4; ++j) {
      size_t base = (size_t)(m0 + wr * 64 + i * 16 + crow) * N + (n0 + wc * 64 + j * 16 + ccol);
      if (BF16OUT) {
        unsigned short* C = (unsigned short*)Cv;
#pragma unroll
        for (int r = 0; r < 4; ++r) C[base + (size_t)r * N] = f2bf(acc[i][j][r]);
      } else {
        float* C = (float*)Cv;
#pragma unroll
        for (int r = 0; r < 4; ++r) C[base + (size_t)r * N] = acc[i][j][r];
      }
    }
}

// ---------------- conv1d + silu ----------------
__global__ __launch_bounds__(256) void k_conv_silu(const unsigned short* __restrict__ xb,
                                                   const unsigned short* __restrict__ wT,
                                                   const unsigned short* __restrict__ bT,
                                                   unsigned short* __restrict__ out) {
  long idx = (long)blockIdx.x * blockDim.x + threadIdx.x;
  if (idx >= (long)(NROWS / 4) * CG) return;
  int c8 = (int)(idx % CG);
  long rq = idx / CG;
  int l0 = (int)((rq & (SEQ / 4 - 1)) * 4);
  long brow = (rq >> 9) * (long)SEQ;
  int ch0 = c8 * 8;

  u16x8 wv[4];
#pragma unroll
  for (int w = 0; w < 4; ++w) wv[w] = *(const u16x8*)(wT + w * CONV_DIM + ch0);
  u16x8 bv = *(const u16x8*)(bT + ch0);

  u16x8 xr[7];
#pragma unroll
  for (int i = 0; i < 7; ++i) {
    int ls = l0 - 3 + i;
    if (ls >= 0) xr[i] = *(const u16x8*)(xb + (brow + ls) * (long)CONV_DIM + ch0);
    else { u16x8 z = {0, 0, 0, 0, 0, 0, 0, 0}; xr[i] = z; }
  }

#pragma unroll
  for (int r = 0; r < 4; ++r) {
    float acc[8];
#pragma unroll
    for (int e = 0; e < 8; ++e) acc[e] = bf2f(bv[e]);
#pragma unroll
    for (int w = 0; w < 4; ++w)
#pragma unroll
      for (int e = 0; e < 8; ++e) acc[e] += bf2f(xr[r + w][e]) * bf2f(wv[w][e]);
    u16x8 o;
#pragma unroll
    for (int e = 0; e < 8; ++e) o[e] = f2bf(acc[e] / (1.f + __expf(-acc[e])));
    *(u16x8*)(out + (brow + l0 + r) * (long)CONV_DIM + ch0) = o;
  }
}

// ---- CBT tiled layout: idx(l,s) = ((l>>4)*32 + (s>>3))*128 + (l&15)*8 + (s&7) ----
__global__ __launch_bounds__(256) void k_cbtt(const unsigned short* __restrict__ xbc, unsigned short* __restrict__ cbt_t) {
  const int bid = blockIdx.x;
  const int sp = bid & 3;
  const int bc = bid >> 2;
  const int b = bc >> 3, c = bc & 7;
  const int t = threadIdx.x;
  const int lane = t & 63;
  const int w = t >> 6;
  const int g = lane >> 4;
  __shared__ unsigned short Cs[256][72];
  __shared__ unsigned short Bs2[64][72];
  const long rowbase = (long)b * SEQ + c * CHUNK;
  f32x4 acc[4][4];
#pragma unroll
  for (int i = 0; i < 4; ++i)
#pragma unroll
    for (int j = 0; j < 4; ++j) { f32x4 z = {0.f, 0.f, 0.f, 0.f}; acc[i][j] = z; }

  for (int np = 0; np < 2; ++np) {
    __syncthreads();
    for (int i = t; i < 256 * 16; i += 256) {
      int row = i >> 4, c4 = (i & 15) * 4;
      ushort4 v = *(const ushort4*)(xbc + (rowbase + row) * (long)CONV_DIM + D_INNER + D_STATE + np * 64 + c4);
      *(ushort4*)&Cs[row][c4] = v;
    }
    for (int i = t; i < 64 * 16; i += 256) {
      int row = i >> 4, c4 = (i & 15) * 4;
      ushort4 v = *(const ushort4*)(xbc + (rowbase + sp * 64 + row) * (long)CONV_DIM + D_INNER + np * 64 + c4);
      *(ushort4*)&Bs2[row][c4] = v;
    }
    __syncthreads();
#pragma unroll
    for (int ks = 0; ks < 2; ++ks) {
      const int kofs = ks * 32 + g * 8;
      bf16x8 af[4], bfr[4];
#pragma unroll
      for (int i = 0; i < 4; ++i) af[i] = *(const bf16x8*)&Cs[w * 64 + i * 16 + (lane & 15)][kofs];
#pragma unroll
      for (int j = 0; j < 4; ++j) bfr[j] = *(const bf16x8*)&Bs2[j * 16 + (lane & 15)][kofs];
#pragma unroll
      for (int i = 0; i < 4; ++i)
#pragma unroll
        for (int j = 0; j < 4; ++j)
          acc[i][j] = __builtin_amdgcn_mfma_f32_16x16x32_bf16(af[i], bfr[j], acc[i][j], 0, 0, 0);
    }
  }
  unsigned short* ob = cbt_t + (long)bc * CHUNK * CHUNK;
#pragma unroll
  for (int i = 0; i < 4; ++i)
#pragma unroll
    for (int j = 0; j < 4; ++j) {
      int l0 = w * 64 + i * 16 + g * 4;
      int s = sp * 64 + j * 16 + (lane & 15);
#pragma unroll
      for (int r = 0; r < 4; ++r) {
        int l = l0 + r;
        ob[((long)(l >> 4) * 32 + (s >> 3)) * 128 + (l & 15) * 8 + (s & 7)] = f2bf(acc[i][j][r]);
      }
    }
}

// ---- states[n][p], MFMA, XOR-swizzled transpose staging ----
__global__ __launch_bounds__(256) void k_states(const unsigned short* __restrict__ xbc, const float* __restrict__ dt_t,
                                                const float* __restrict__ A_cum, float* __restrict__ states) {
  const int bid = blockIdx.x;
  const int h = bid & 63;
  const int bc = bid >> 6;
  const int b = bc >> 3, c = bc & 7;
  const int t = threadIdx.x;
  const int lane = t & 63;
  const int w = t >> 6;
  const int g = lane >> 4;
  __shared__ unsigned short BT[128][72];
  __shared__ unsigned short WXT[64][72];
  __shared__ float csL[256], dtL[256];
  const long rowbase = (long)b * SEQ + c * CHUNK;
  const long bh8 = ((long)(b * NHEADS + h)) * NCHUNK + c;
  const float* acum = A_cum + bh8 * CHUNK;
  if (t < 256) { csL[t] = acum[t]; dtL[t] = dt_t[((size_t)(b * NHEADS + h)) * SEQ + c * CHUNK + t]; }
  float cs_last = acum[255];
  f32x4 acc[2][4];
#pragma unroll
  for (int i = 0; i < 2; ++i)
#pragma unroll
    for (int j = 0; j < 4; ++j) { f32x4 z = {0.f, 0.f, 0.f, 0.f}; acc[i][j] = z; }

  for (int lp = 0; lp < 4; ++lp) {
    __syncthreads();
    for (int i = t; i < 64 * 32; i += 256) {
      int l = i >> 5, n4 = (i & 31) * 4;
      int sw = ((n4 >> 3) & 7) << 3;
      ushort4 v = *(const ushort4*)(xbc + (rowbase + lp * 64 + l) * (long)CONV_DIM + D_INNER + n4);
      BT[n4 + 0][l ^ sw] = v.x; BT[n4 + 1][l ^ sw] = v.y; BT[n4 + 2][l ^ sw] = v.z; BT[n4 + 3][l ^ sw] = v.w;
    }
    for (int i = t; i < 64 * 16; i += 256) {
      int l = i >> 4, p4 = (i & 15) * 4;
      int sw = ((p4 >> 3) & 7) << 3;
      int lg = lp * 64 + l;
      float wgt = __expf(cs_last - csL[lg]) * dtL[lg];
      ushort4 v = *(const ushort4*)(xbc + (rowbase + lg) * (long)CONV_DIM + h * HEADDIM + p4);
      WXT[p4 + 0][l ^ sw] = f2bf(bf2f(v.x) * wgt);
      WXT[p4 + 1][l ^ sw] = f2bf(bf2f(v.y) * wgt);
      WXT[p4 + 2][l ^ sw] = f2bf(bf2f(v.z) * wgt);
      WXT[p4 + 3][l ^ sw] = f2bf(bf2f(v.w) * wgt);
    }
    __syncthreads();
#pragma unroll
    for (int ks = 0; ks < 2; ++ks) {
      const int kofs = ks * 32 + g * 8;
      bf16x8 am[2], bp[4];
#pragma unroll
      for (int i = 0; i < 2; ++i) {
        int row = w * 32 + i * 16 + (lane & 15);
        am[i] = *(const bf16x8*)&BT[row][kofs ^ (((row >> 3) & 7) << 3)];
      }
#pragma unroll
      for (int j = 0; j < 4; ++j) {
        int row = j * 16 + (lane & 15);
        bp[j] = *(const bf16x8*)&WXT[row][kofs ^ (((row >> 3) & 7) << 3)];
      }
#pragma unroll
      for (int i = 0; i < 2; ++i)
#pragma unroll
        for (int j = 0; j < 4; ++j)
          acc[i][j] = __builtin_amdgcn_mfma_f32_16x16x32_bf16(am[i], bp[j], acc[i][j], 0, 0, 0);
    }
  }
  float* sp = states + ((long)bc * NHEADS + h) * (D_STATE * HEADDIM);
#pragma unroll
  for (int i = 0; i < 2; ++i)
#pragma unroll
    for (int j = 0; j < 4; ++j) {
      int n0 = w * 32 + i * 16 + g * 4;
      int p = j * 16 + (lane & 15);
#pragma unroll
      for (int r = 0; r < 4; ++r) sp[(long)(n0 + r) * HEADDIM + p] = acc[i][j][r];
    }
}

// ---------------- inter-chunk scan -> prev_states (bf16, [n][p]) ----------------
__global__ void k_scan(const float* __restrict__ states, const float* __restrict__ A_cum, unsigned short* __restrict__ psb) {
  long idx = (long)blockIdx.x * blockDim.x + threadIdx.x;
  if (idx >= (long)BATCH * NHEADS * D_STATE * HEADDIM) return;
  int p = idx & 63;
  int n = (int)((idx >> 6) & 127);
  long bh = idx >> 13;
  int h = (int)(bh & 63);
  int b = (int)(bh >> 6);
  float S = 0.f;
  for (int c = 0; c < NCHUNK; ++c) {
    long soff = (((long)(b * NCHUNK + c) * NHEADS + h) * (D_STATE * HEADDIM)) + (long)n * HEADDIM + p;
    psb[soff] = f2bf(S);
    float decay = __expf(A_cum[(bh * NCHUNK + c) * CHUNK + 255]);
    S = S * decay + states[soff];
  }
}

// ---- Y = Y_diag + Y_off + x*D: balanced waves, swizzled LDS, tiled cbt ----
__global__ __launch_bounds__(256) void k_y(const unsigned short* __restrict__ xbc, const float* __restrict__ dt_t,
                                           const float* __restrict__ A_cum, const unsigned short* __restrict__ cbt_t,
                                           const unsigned short* __restrict__ psb, const float* __restrict__ Dp,
                                           unsigned short* __restrict__ y) {
  const int bid = blockIdx.x;
  const int h = bid & 63;
  const int bc = bid >> 6;
  const int b = bc >> 3, c = bc & 7;
  const int t = threadIdx.x;
  const int lane = t & 63;
  const int w = t >> 6;
  const int g = lane >> 4;
  __shared__ unsigned short Abuf[256][56];
  __shared__ unsigned short Bbuf[64][72];
  __shared__ float csL[256], dtL[256], expL[256];
  const long rowbase = (long)b * SEQ + c * CHUNK;
  const long bh8 = ((long)(b * NHEADS + h)) * NCHUNK + c;
  const float* acum = A_cum + bh8 * CHUNK;
  if (t < 256) {
    float cv = acum[t];
    csL[t] = cv;
    expL[t] = __expf(cv);
    dtL[t] = dt_t[((size_t)(b * NHEADS + h)) * SEQ + c * CHUNK + t];
  }
  f32x4 acc[4][4];
#pragma unroll
  for (int i = 0; i < 4; ++i)
#pragma unroll
    for (int j = 0; j < 4; ++j) { f32x4 z = {0.f, 0.f, 0.f, 0.f}; acc[i][j] = z; }

  const unsigned short* psbase = psb + ((long)bc * NHEADS + h) * (D_STATE * HEADDIM);
  for (int np = 0; np < 4; ++np) {
    __syncthreads();
    for (int i = t; i < 256 * 8; i += 256) {
      int row = i >> 3, c4 = (i & 7) * 4;
      float el = expL[row];
      ushort4 v = *(const ushort4*)(xbc + (rowbase + row) * (long)CONV_DIM + D_INNER + D_STATE + np * 32 + c4);
      ushort4 o = make_ushort4(f2bf(bf2f(v.x) * el), f2bf(bf2f(v.y) * el), f2bf(bf2f(v.z) * el), f2bf(bf2f(v.w) * el));
      *(ushort4*)&Abuf[row][c4] = o;
    }
    for (int i = t; i < 512; i += 256) {
      int nl = i >> 4, p4 = (i & 15) * 4;
      int sw = ((p4 >> 3) & 7) << 3;
      ushort4 v = *(const ushort4*)(psbase + (long)(np * 32 + nl) * HEADDIM + p4);
      Bbuf[p4 + 0][nl ^ sw] = v.x; Bbuf[p4 + 1][nl ^ sw] = v.y;
      Bbuf[p4 + 2][nl ^ sw] = v.z; Bbuf[p4 + 3][nl ^ sw] = v.w;
    }
    __syncthreads();
    bf16x8 bfr[4];
#pragma unroll
    for (int j = 0; j < 4; ++j) {
      int row = j * 16 + (lane & 15);
      bfr[j] = *(const bf16x8*)&Bbuf[row][(g * 8) ^ (((row >> 3) & 7) << 3)];
    }
#pragma unroll
    for (int i = 0; i < 4; ++i) {
      bf16x8 af = *(const bf16x8*)&Abuf[(i * 4 + w) * 16 + (lane & 15)][g * 8];
#pragma unroll
      for (int j = 0; j < 4; ++j)
        acc[i][j] = __builtin_amdgcn_mfma_f32_16x16x32_bf16(af, bfr[j], acc[i][j], 0, 0, 0);
    }
  }

  const unsigned short* cbtb = cbt_t + (long)bc * CHUNK * CHUNK;
  for (int sp = 0; sp < 4; ++sp) {
    __syncthreads();
    for (int i = t; i < 512; i += 256) {
      int s = i >> 3, p0 = (i & 7) * 8;
      int sw = ((p0 >> 3) & 7) << 3;
      u16x8 v = *(const u16x8*)(xbc + (rowbase + sp * 64 + s) * (long)CONV_DIM + h * HEADDIM + p0);
#pragma unroll
      for (int e = 0; e < 8; ++e) Bbuf[p0 + e][s ^ sw] = v[e];
    }
    __syncthreads();
#pragma unroll
    for (int ks = 0; ks < 2; ++ks) {
      const int sb0 = sp * 64 + ks * 32;
      bf16x8 bfr[4];
#pragma unroll
      for (int j = 0; j < 4; ++j) {
        int row = j * 16 + (lane & 15);
        bfr[j] = *(const bf16x8*)&Bbuf[row][(ks * 32 + g * 8) ^ (((row >> 3) & 7) << 3)];
      }
      const int sbase = sb0 + g * 8;
#pragma unroll
      for (int i = 0; i < 4; ++i) {
        const int L0 = (i * 4 + w) * 16;
        if (sb0 > L0 + 15) continue;
        const int l = L0 + (lane & 15);
        u16x8 cv = *(const u16x8*)(cbtb + ((long)(L0 >> 4) * 32 + (sbase >> 3)) * 128 + (l & 15) * 8);
        const float cl = csL[l];
        bf16x8 af;
#pragma unroll
        for (int e = 0; e < 8; ++e) {
          int s = sbase + e;
          float val = (s <= l) ? bf2f(cv[e]) * __expf(cl - csL[s]) * dtL[s] : 0.f;
          af[e] = (short)f2bf(val);
        }
#pragma unroll
        for (int j = 0; j < 4; ++j)
          acc[i][j] = __builtin_amdgcn_mfma_f32_16x16x32_bf16(af, bfr[j], acc[i][j], 0, 0, 0);
      }
    }
  }

  const float Dh = Dp[h];
#pragma unroll
  for (int i = 0; i < 4; ++i) {
    int l0 = (i * 4 + w) * 16 + g * 4;
#pragma unroll
    for (int r = 0; r < 4; ++r) {
      long grow = rowbase + l0 + r;
      const unsigned short* xrow = xbc + grow * (long)CONV_DIM + h * HEADDIM;
      unsigned short* yrow = y + grow * (long)D_INNER + h * HEADDIM;
#pragma unroll
      for (int j = 0; j < 4; ++j) {
        int p = j * 16 + (lane & 15);
        yrow[p] = f2bf(acc[i][j][r] + bf2f(xrow[p]) * Dh);
      }
    }
  }
}

// ---------------- gated RMSNorm ----------------
__global__ __launch_bounds__(256) void k_norm(unsigned short* yz, const unsigned short* __restrict__ zb,
                                              const float* __restrict__ norm_w, unsigned short* out) {
  const int row = blockIdx.x;
  const int t = threadIdx.x;
  const unsigned short* yr = yz + (size_t)row * D_INNER;
  const unsigned short* zr = zb + (size_t)row * D_INNER;
  float yv[16];
  float ss = 0.f;
#pragma unroll
  for (int j = 0; j < 4; ++j) {
    int e = (t + j * 256) * 4;
    ushort4 yy = *(const ushort4*)(yr + e);
    ushort4 zz = *(const ushort4*)(zr + e);
    float z0 = bf2f(zz.x), z1 = bf2f(zz.y), z2 = bf2f(zz.z), z3 = bf2f(zz.w);
    float g0 = bf2f(yy.x) * z0 / (1.f + __expf(-z0));
    float g1 = bf2f(yy.y) * z1 / (1.f + __expf(-z1));
    float g2 = bf2f(yy.z) * z2 / (1.f + __expf(-z2));
    float g3 = bf2f(yy.w) * z3 / (1.f + __expf(-z3));
    ss += g0 * g0 + g1 * g1 + g2 * g2 + g3 * g3;
    yv[j * 4 + 0] = g0; yv[j * 4 + 1] = g1; yv[j * 4 + 2] = g2; yv[j * 4 + 3] = g3;
  }
#pragma unroll
  for (int off = 32; off > 0; off >>= 1) ss += __shfl_xor(ss, off);
  __shared__ float red[4];
  if ((t & 63) == 0) red[t >> 6] = ss;
  __syncthreads();
  float tot = red[0] + red[1] + red[2] + red[3];
  float scale = rsqrtf(tot / (float)D_INNER + EPSV);
  unsigned short* orow = out + (size_t)row * D_INNER;
#pragma unroll
  for (int j = 0; j < 4; ++j) {
    int e = (t + j * 256) * 4;
    float4 w = *(const float4*)(norm_w + e);
    ushort4 o = make_ushort4(f2bf(yv[j * 4 + 0] * scale * w.x), f2bf(yv[j * 4 + 1] * scale * w.y),
                             f2bf(yv[j * 4 + 2] * scale * w.z), f2bf(yv[j * 4 + 3] * scale * w.w));
    *(ushort4*)(orow + e) = o;
  }
}

extern "C" void kernel_launch(void* const* d_in, const int* in_sizes, int n_in,
                              void* d_out, int out_size, void* d_ws, size_t ws_size,
                              hipStream_t stream) {
  const float* u       = (const float*)d_in[0];
  const float* W_in    = (const float*)d_in[1];
  const float* conv_w  = (const float*)d_in[2];
  const float* conv_b  = (const float*)d_in[3];
  const float* dt_bias = (const float*)d_in[4];
  const float* A_log   = (const float*)d_in[5];
  const float* Dp      = (const float*)d_in[6];
  const float* norm_w  = (const float*)d_in[7];
  const float* W_out   = (const float*)d_in[8];
  float* out = (float*)d_out;

  char* ws = (char*)d_ws;
  size_t off = 0;
  auto alloc = [&](size_t bytes) { char* p = ws + off; off += (bytes + 255) & ~(size_t)255; return p; };
  unsigned short* ub   = (unsigned short*)alloc((size_t)NROWS * D_MODEL * 2);
  unsigned short* winb = (unsigned short*)alloc((size_t)D_IN_PROJ * D_MODEL * 2);
  unsigned short* zb   = (unsigned short*)alloc((size_t)NROWS * D_INNER * 2);
  unsigned short* xb   = (unsigned short*)alloc((size_t)NROWS * CONV_DIM * 2);
  unsigned short* xbcb = (unsigned short*)alloc((size_t)NROWS * CONV_DIM * 2);
  float* dtt  = (float*)alloc((size_t)BATCH * NHEADS * SEQ * 4);
  float* acum = (float*)alloc((size_t)BATCH * NHEADS * NCHUNK * CHUNK * 4);
  unsigned short* cwT = (unsigned short*)alloc((size_t)4 * CONV_DIM * 2);
  unsigned short* cbT = (unsigned short*)alloc((size_t)CONV_DIM * 2);
  unsigned short* whl = (unsigned short*)alloc((size_t)128 * D_MODEL * 2);
  float* PD = (float*)alloc((size_t)4 * BATCH * NHEADS * SEQ * 4);
  unsigned short* wob = ub;
  unsigned short* cbt = winb;
  unsigned short* psb = winb + (size_t)BATCH * NCHUNK * CHUNK * CHUNK + 1024;
  unsigned short* ulob = xbcb;
  unsigned short* yb = xb;
  float* states = (float*)d_out;

  if (off > ws_size) {
    k_sentinel<<<1, 64, 0, stream>>>(out);
    return;
  }

  k_prep<<<6673, 256, 0, stream>>>(u, ub, ulob, W_in, winb, whl, conv_w, conv_b, cwT, cbT);
  k_gemm8p<<<(NROWS / 256) * (D_INNER / 256), 512, 0, stream>>>(ub, winb, zb, NROWS, D_INNER, D_MODEL);
  k_gemm128<1><<<(NROWS / 128) * (CONV_DIM / 128), 256, 0, stream>>>(ub, winb + (size_t)D_INNER * D_MODEL, xb, NROWS, CONV_DIM, D_MODEL);
  k_dtm<<<256, 256, 0, stream>>>(ub, ulob, whl, PD);
  k_dtred<<<BATCH * NHEADS, 256, 0, stream>>>(PD, dt_bias, A_log, dtt, acum);
  k_conv_silu<<<(int)(((long)(NROWS / 4) * CG + 255) / 256), 256, 0, stream>>>(xb, cwT, cbT, xbcb);
  k_cbtt<<<BATCH * NCHUNK * 4, 256, 0, stream>>>(xbcb, cbt);
  k_states<<<BATCH * NCHUNK * NHEADS, 256, 0, stream>>>(xbcb, dtt, acum, states);
  k_scan<<<(BATCH * NHEADS * D_STATE * HEADDIM + 255) / 256, 256, 0, stream>>>(states, acum, psb);
  k_y<<<BATCH * NCHUNK * NHEADS, 256, 0, stream>>>(xbcb, dtt, acum, cbt, psb, Dp, yb);
  k_norm<<<NROWS, 256, 0, stream>>>(yb, zb, norm_w, yb);
  k_f32_to_bf16_v4<<<2048, 256, 0, stream>>>(W_out, wob, (long)D_MODEL * D_INNER / 4);
  k_gemm128<0><<<(NROWS / 128) * (D_MODEL / 128), 256, 0, stream>>>(yb, wob, out, NROWS, D_MODEL, D_INNER);
}

// Round 13
// 437.785 us; speedup vs baseline: 1.0534x; 1.0534x over previous
//
#include <hip/hip_runtime.h>

#define D_MODEL   2048
#define D_INNER   4096
#define HEADDIM   64
#define NHEADS    64
#define D_STATE   128
#define CHUNK     256
#define CONV_DIM  4352
#define D_IN_PROJ 8512
#define BATCH     2
#define SEQ       2048
#define NCHUNK    8
#define NROWS     4096
#define EPSV      1e-5f
#define CG        (CONV_DIM / 8)   // 544

typedef __attribute__((ext_vector_type(8))) short bf16x8;
typedef __attribute__((ext_vector_type(8))) unsigned short u16x8;
typedef __attribute__((ext_vector_type(4))) float f32x4;

#define AS1 __attribute__((address_space(1)))
#define AS3 __attribute__((address_space(3)))

#define BAR() do { asm volatile("" ::: "memory"); __builtin_amdgcn_s_barrier(); asm volatile("" ::: "memory"); } while (0)

__device__ __forceinline__ unsigned short f2bf(float f) {
  unsigned int x = __float_as_uint(f);
  unsigned int r = (x + 0x7fffu + ((x >> 16) & 1u)) >> 16;
  return (unsigned short)r;
}
__device__ __forceinline__ float bf2f(unsigned short u) {
  return __uint_as_float((unsigned int)u << 16);
}

__global__ void k_sentinel(float* out) { if (threadIdx.x == 0) out[0] = 1.0e6f; }

// ---------------- fused prep: usplit | W_in convert | wpack | conv pack ----------------
__global__ void k_prep(const float* __restrict__ u, unsigned short* __restrict__ uhi, unsigned short* __restrict__ ulo,
                       const float* __restrict__ W, unsigned short* __restrict__ winb, unsigned short* __restrict__ whl,
                       const float* __restrict__ cw, const float* __restrict__ cb,
                       unsigned short* __restrict__ cwT, unsigned short* __restrict__ cbT) {
  const int b = blockIdx.x;
  const int t = threadIdx.x;
  if (b < 2048) {
    const long n4 = (long)NROWS * D_MODEL / 4;
    for (long i = (long)b * 256 + t; i < n4; i += 2048L * 256) {
      float4 v = ((const float4*)u)[i];
      ushort4 h, l;
      h.x = f2bf(v.x); l.x = f2bf(v.x - bf2f(h.x));
      h.y = f2bf(v.y); l.y = f2bf(v.y - bf2f(h.y));
      h.z = f2bf(v.z); l.z = f2bf(v.z - bf2f(h.z));
      h.w = f2bf(v.w); l.w = f2bf(v.w - bf2f(h.w));
      ((ushort4*)uhi)[i] = h;
      ((ushort4*)ulo)[i] = l;
    }
  } else if (b < 6144) {
    const long n4 = (long)D_IN_PROJ * D_MODEL / 4;
    for (long i = (long)(b - 2048) * 256 + t; i < n4; i += 4096L * 256) {
      float4 v = ((const float4*)W)[i];
      ushort4 o = make_ushort4(f2bf(v.x), f2bf(v.y), f2bf(v.z), f2bf(v.w));
      ((ushort4*)winb)[i] = o;
    }
  } else if (b < 6656) {
    long i = (long)(b - 6144) * 256 + t;
    float v = W[(size_t)8448 * D_MODEL + i];
    unsigned short h = f2bf(v);
    whl[i] = h;
    whl[(size_t)64 * D_MODEL + i] = f2bf(v - bf2f(h));
  } else {
    int i = (b - 6656) * 256 + t;
    if (i < CONV_DIM) {
#pragma unroll
      for (int w = 0; w < 4; ++w) cwT[w * CONV_DIM + i] = f2bf(cw[i * 4 + w]);
      cbT[i] = f2bf(cb[i]);
    }
  }
}

// ---------------- W_out convert ----------------
__global__ void k_f32_to_bf16_v4(const float* __restrict__ in, unsigned short* __restrict__ out, long n4) {
  long i = (long)blockIdx.x * blockDim.x + threadIdx.x;
  long stride = (long)gridDim.x * blockDim.x;
  for (; i < n4; i += stride) {
    float4 v = ((const float4*)in)[i];
    ushort4 o = make_ushort4(f2bf(v.x), f2bf(v.y), f2bf(v.z), f2bf(v.w));
    ((ushort4*)out)[i] = o;
  }
}

// ---- dt split-bf16 MFMA, SPLIT-K=4 -> PD[ks][bh][l] (f32) ----
__global__ __launch_bounds__(256, 2) void k_dtm(const unsigned short* __restrict__ uhi,
                                                const unsigned short* __restrict__ ulo,
                                                const unsigned short* __restrict__ whl,
                                                float* __restrict__ PD) {
  __shared__ __align__(16) short lds[2][256 * 64];
  const int t = threadIdx.x;
  const int lane = t & 63;
  const int w = t >> 6;
  const int ks = (int)blockIdx.x & 3;
  const int m0 = ((int)blockIdx.x >> 2) * 64;
  const int kbase = ks * 512;

  f32x4 acc1[8], acc2[4];
#pragma unroll
  for (int j = 0; j < 8; ++j) { f32x4 z = {0.f, 0.f, 0.f, 0.f}; acc1[j] = z; }
#pragma unroll
  for (int j = 0; j < 4; ++j) { f32x4 z = {0.f, 0.f, 0.f, 0.f}; acc2[j] = z; }

  const int srow = t >> 3;
  const int schunk = (t & 7) ^ (srow & 7);
  const unsigned short* gU = uhi + (size_t)(m0 + srow) * D_MODEL + kbase + schunk * 8;
  const unsigned short* gL = ulo + (size_t)(m0 + srow) * D_MODEL + kbase + schunk * 8;
  const unsigned short* gW = whl + (size_t)srow * D_MODEL + kbase + schunk * 8;

  auto STAGE = [&](int buf, int kt) {
    char* d = (char*)&lds[buf][0] + t * 16;
#pragma unroll
    for (int ii = 0; ii < 2; ++ii)
      __builtin_amdgcn_global_load_lds((const AS1 void*)(gU + (size_t)ii * 32 * D_MODEL + (size_t)kt * 64),
                                       (AS3 void*)(d + ii * 4096), 16, 0, 0);
#pragma unroll
    for (int ii = 0; ii < 2; ++ii)
      __builtin_amdgcn_global_load_lds((const AS1 void*)(gL + (size_t)ii * 32 * D_MODEL + (size_t)kt * 64),
                                       (AS3 void*)(d + 8192 + ii * 4096), 16, 0, 0);
#pragma unroll
    for (int ii = 0; ii < 4; ++ii)
      __builtin_amdgcn_global_load_lds((const AS1 void*)(gW + (size_t)ii * 32 * D_MODEL + (size_t)kt * 64),
                                       (AS3 void*)(d + 16384 + ii * 4096), 16, 0, 0);
  };

  STAGE(0, 0);

  const int NT = 512 / 64;
  const int ar = w * 16 + (lane & 15);
  const int kof = (lane >> 4) * 8;
  const int rsw = (lane & 7) * 8;
  int cur = 0;
  for (int kt = 0; kt < NT; ++kt) {
    if (kt + 1 < NT) {
      STAGE(cur ^ 1, kt + 1);
      asm volatile("s_waitcnt vmcnt(8)" ::: "memory");
    } else {
      asm volatile("s_waitcnt vmcnt(0)" ::: "memory");
    }
    __builtin_amdgcn_s_barrier();
    asm volatile("" ::: "memory");
    const short* L = &lds[cur][0];
#pragma unroll
    for (int kk = 0; kk < 2; ++kk) {
      const int off = (kk * 32 + kof) ^ rsw;
      bf16x8 ah = *(const bf16x8*)(L + ar * 64 + off);
      bf16x8 al = *(const bf16x8*)(L + (64 + ar) * 64 + off);
#pragma unroll
      for (int j = 0; j < 8; ++j) {
        bf16x8 bj = *(const bf16x8*)(L + (128 + j * 16 + (lane & 15)) * 64 + off);
        acc1[j] = __builtin_amdgcn_mfma_f32_16x16x32_bf16(ah, bj, acc1[j], 0, 0, 0);
        if (j < 4) acc2[j] = __builtin_amdgcn_mfma_f32_16x16x32_bf16(al, bj, acc2[j], 0, 0, 0);
      }
    }
    asm volatile("" ::: "memory");
    __builtin_amdgcn_s_barrier();
    asm volatile("" ::: "memory");
    cur ^= 1;
  }

  const int crow = (lane >> 4) * 4;
  float* P = PD + (size_t)ks * BATCH * NHEADS * SEQ;
#pragma unroll
  for (int j = 0; j < 4; ++j) {
    int h = j * 16 + (lane & 15);
#pragma unroll
    for (int r = 0; r < 4; ++r) {
      int row = m0 + w * 16 + crow + r;
      float v = acc1[j][r] + acc1[j + 4][r] + acc2[j][r];
      P[(size_t)((row >> 11) * NHEADS + h) * SEQ + (row & 2047)] = v;
    }
  }
}

// ---- dt reduce + softplus -> dtt; fused per-chunk cumsum -> acum ----
__global__ __launch_bounds__(256) void k_dtred(const float* __restrict__ PD, const float* __restrict__ dt_bias,
                                               const float* __restrict__ A_log,
                                               float* __restrict__ dt_t, float* __restrict__ A_cum) {
  const int bh = blockIdx.x;
  const int h = bh & 63;
  const int t = threadIdx.x;
  const float bias = dt_bias[h];
  const float A = -__expf(A_log[h]);
  const size_t base = (size_t)bh * SEQ;
  const size_t pstride = (size_t)BATCH * NHEADS * SEQ;
  __shared__ float s[256];
  for (int c = 0; c < NCHUNK; ++c) {
    int l = c * CHUNK + t;
    float v = PD[base + l] + PD[pstride + base + l] + PD[2 * pstride + base + l] + PD[3 * pstride + base + l] + bias;
    float dtv = (v > 20.f) ? v : log1pf(expf(v));
    dt_t[base + l] = dtv;
    s[t] = dtv * A;
    __syncthreads();
    for (int off = 1; off < 256; off <<= 1) {
      float x = (t >= off) ? s[t - off] : 0.f;
      __syncthreads();
      s[t] += x;
      __syncthreads();
    }
    A_cum[((size_t)bh * NCHUNK + c) * CHUNK + t] = s[t];
    __syncthreads();
  }
}

// ---- 256x256 BK=64 8-phase GEMM (T2+T3+T4+T5), grouped-raster XCD swizzle ----
__global__ __launch_bounds__(512, 2) void k_gemm8p(const unsigned short* __restrict__ A,
                                                   const unsigned short* __restrict__ B,
                                                   unsigned short* __restrict__ C, int M, int N, int K) {
  __shared__ __align__(16) short lds[2][32768];
  const int t = threadIdx.x;
  const int lane = t & 63;
  const int wid = t >> 6;
  const int wr = wid >> 2;
  const int wc = wid & 3;
  const int ntx = N / 256;
  const int nwg = (int)gridDim.x;
  const int bid = (int)blockIdx.x;
  const int swz = (bid & 7) * (nwg >> 3) + (bid >> 3);
  const int grp = ntx << 3;
  const int gid = swz / grp;
  const int rem = swz - gid * grp;
  const int m0 = ((gid << 3) + (rem & 7)) * 256;
  const int n0 = (rem >> 3) * 256;

  f32x4 acc[8][4];
#pragma unroll
  for (int i = 0; i < 8; ++i)
#pragma unroll
    for (int j = 0; j < 4; ++j) { f32x4 z = {0.f, 0.f, 0.f, 0.f}; acc[i][j] = z; }

  const int srow = t >> 3;
  const int schunk = (t & 7) ^ (srow & 7);
  const unsigned short* gA = A + (size_t)(m0 + srow) * K + schunk * 8;
  const unsigned short* gB = B + (size_t)(n0 + srow) * K + schunk * 8;

  auto STAGE_HALF = [&](int buf, int kt, int which) {
    const unsigned short* g = (which < 2 ? gA : gB) + (size_t)(which & 1) * 128 * K + (size_t)kt * 64;
    char* d = (char*)lds + buf * 65536 + which * 16384 + t * 16;
    __builtin_amdgcn_global_load_lds((const AS1 void*)g, (AS3 void*)d, 16, 0, 0);
    __builtin_amdgcn_global_load_lds((const AS1 void*)(g + (size_t)64 * K), (AS3 void*)(d + 8192), 16, 0, 0);
  };

  const int NT = K / 64;
  STAGE_HALF(0, 0, 0); STAGE_HALF(0, 0, 1); STAGE_HALF(0, 0, 2); STAGE_HALF(0, 0, 3);
  STAGE_HALF(1, 1, 2); STAGE_HALF(1, 1, 0); STAGE_HALF(1, 1, 1);
  asm volatile("s_waitcnt vmcnt(6)" ::: "memory");
  BAR();

  const int ar = wr * 128 + (lane & 15);
  const int br = wc * 64 + (lane & 15);
  const int kof = (lane >> 4) * 8;
  const int rsw = (lane & 7) * 8;

  for (int kt = 0; kt < NT; ++kt) {
    const int buf = kt & 1;
    const short* As = &lds[buf][0];
    const short* Bs = &lds[buf][16384];
    const bool s1 = (kt + 1 < NT);
    const bool s2 = (kt + 2 < NT);
    bf16x8 aLo[4][2], aHi[4][2], bLo[2][2], bHi[2][2];

#pragma unroll
    for (int i = 0; i < 4; ++i)
#pragma unroll
      for (int k = 0; k < 2; ++k) aLo[i][k] = *(const bf16x8*)(As + (ar + i * 16) * 64 + ((k * 32 + kof) ^ rsw));
#pragma unroll
    for (int j = 0; j < 2; ++j)
#pragma unroll
      for (int k = 0; k < 2; ++k) bLo[j][k] = *(const bf16x8*)(Bs + (br + j * 16) * 64 + ((k * 32 + kof) ^ rsw));
    if (s1) STAGE_HALF(buf ^ 1, kt + 1, 3);
    BAR();
    __builtin_amdgcn_s_setprio(1);
#pragma unroll
    for (int k = 0; k < 2; ++k)
#pragma unroll
      for (int i = 0; i < 4; ++i)
#pragma unroll
        for (int j = 0; j < 2; ++j)
          acc[i][j] = __builtin_amdgcn_mfma_f32_16x16x32_bf16(aLo[i][k], bLo[j][k], acc[i][j], 0, 0, 0);
    __builtin_amdgcn_s_setprio(0);
    BAR();

#pragma unroll
    for (int j = 0; j < 2; ++j)
#pragma unroll
      for (int k = 0; k < 2; ++k) bHi[j][k] = *(const bf16x8*)(Bs + (br + (j + 2) * 16) * 64 + ((k * 32 + kof) ^ rsw));
    BAR();
    __builtin_amdgcn_s_setprio(1);
#pragma unroll
    for (int k = 0; k < 2; ++k)
#pragma unroll
      for (int i = 0; i < 4; ++i)
#pragma unroll
        for (int j = 0; j < 2; ++j)
          acc[i][j + 2] = __builtin_amdgcn_mfma_f32_16x16x32_bf16(aLo[i][k], bHi[j][k], acc[i][j + 2], 0, 0, 0);
    __builtin_amdgcn_s_setprio(0);
    BAR();

#pragma unroll
    for (int i = 0; i < 4; ++i)
#pragma unroll
      for (int k = 0; k < 2; ++k) aHi[i][k] = *(const bf16x8*)(As + (ar + (i + 4) * 16) * 64 + ((k * 32 + kof) ^ rsw));
    if (s2) STAGE_HALF(buf, kt + 2, 2);
    BAR();
    __builtin_amdgcn_s_setprio(1);
#pragma unroll
    for (int k = 0; k < 2; ++k)
#pragma unroll
      for (int i = 0; i < 4; ++i)
#pragma unroll
        for (int j = 0; j < 2; ++j)
          acc[i + 4][j] = __builtin_amdgcn_mfma_f32_16x16x32_bf16(aHi[i][k], bLo[j][k], acc[i + 4][j], 0, 0, 0);
    __builtin_amdgcn_s_setprio(0);
    BAR();

    if (s2) { STAGE_HALF(buf, kt + 2, 0); STAGE_HALF(buf, kt + 2, 1); }
    if (s2) { asm volatile("s_waitcnt vmcnt(6)" ::: "memory"); }
    else    { asm volatile("s_waitcnt vmcnt(0)" ::: "memory"); }
    BAR();
    __builtin_amdgcn_s_setprio(1);
#pragma unroll
    for (int k = 0; k < 2; ++k)
#pragma unroll
      for (int i = 0; i < 4; ++i)
#pragma unroll
        for (int j = 0; j < 2; ++j)
          acc[i + 4][j + 2] = __builtin_amdgcn_mfma_f32_16x16x32_bf16(aHi[i][k], bHi[j][k], acc[i + 4][j + 2], 0, 0, 0);
    __builtin_amdgcn_s_setprio(0);
    BAR();
  }

  const int crow = (lane >> 4) * 4;
  const int ccol = lane & 15;
#pragma unroll
  for (int i = 0; i < 8; ++i)
#pragma unroll
    for (int j = 0; j < 4; ++j) {
      size_t base = (size_t)(m0 + wr * 128 + i * 16 + crow) * N + (n0 + wc * 64 + j * 16 + ccol);
#pragma unroll
      for (int r = 0; r < 4; ++r) C[base + (size_t)r * N] = f2bf(acc[i][j][r]);
    }
}

// ---- 128x128 BK=64 double-buffered GEMM, counted vmcnt, GM=8 grouped raster (round-11 proven) ----
template <int BF16OUT>
__global__ __launch_bounds__(256, 2) void k_gemm128(const unsigned short* __restrict__ A,
                                                    const unsigned short* __restrict__ B,
                                                    void* __restrict__ Cv, int M, int N, int K) {
  constexpr int BK = 64;
  __shared__ __align__(16) short lds[2][256 * BK];
  const int t = threadIdx.x;
  const int lane = t & 63;
  const int wid = t >> 6;
  const int wr = wid >> 1;
  const int wc = wid & 1;
  const int ntx = N / 128;
  const int nwg = (int)gridDim.x;
  const int bid = (int)blockIdx.x;
  const int swz = (bid & 7) * (nwg >> 3) + (bid >> 3);
  const int grp = ntx << 3;            // requires nwg % grp == 0
  const int gid = swz / grp;
  const int rem = swz - gid * grp;
  const int m0 = ((gid << 3) + (rem & 7)) * 128;
  const int n0 = (rem >> 3) * 128;

  f32x4 acc[4][4];
#pragma unroll
  for (int i = 0; i < 4; ++i)
#pragma unroll
    for (int j = 0; j < 4; ++j) { f32x4 z = {0.f, 0.f, 0.f, 0.f}; acc[i][j] = z; }

  const int srow = t >> 3;
  const int schunk = (t & 7) ^ (srow & 7);
  const unsigned short* gA = A + (size_t)(m0 + srow) * K + schunk * 8;
  const unsigned short* gB = B + (size_t)(n0 + srow) * K + schunk * 8;

  auto STAGE = [&](int buf, int kt) {
    char* dA = (char*)&lds[buf][0] + t * 16;
    char* dB = (char*)&lds[buf][128 * BK] + t * 16;
#pragma unroll
    for (int ii = 0; ii < 4; ++ii)
      __builtin_amdgcn_global_load_lds((const AS1 void*)(gA + (size_t)ii * 32 * K + kt * BK),
                                       (AS3 void*)(dA + ii * 4096), 16, 0, 0);
#pragma unroll
    for (int ii = 0; ii < 4; ++ii)
      __builtin_amdgcn_global_load_lds((const AS1 void*)(gB + (size_t)ii * 32 * K + kt * BK),
                                       (AS3 void*)(dB + ii * 4096), 16, 0, 0);
  };

  STAGE(0, 0);

  const int NT = K / BK;
  const int ar = wr * 64 + (lane & 15);
  const int br = wc * 64 + (lane & 15);
  const int kof = (lane >> 4) * 8;
  const int rsw = (lane & 7) * 8;
  int cur = 0;
  for (int kt = 0; kt < NT; ++kt) {
    if (kt + 1 < NT) {
      STAGE(cur ^ 1, kt + 1);
      asm volatile("s_waitcnt vmcnt(8)" ::: "memory");
    } else {
      asm volatile("s_waitcnt vmcnt(0)" ::: "memory");
    }
    __builtin_amdgcn_s_barrier();
    asm volatile("" ::: "memory");
    const short* As = &lds[cur][0];
    const short* Bs = &lds[cur][128 * BK];
#pragma unroll
    for (int kk = 0; kk < 2; ++kk) {
      bf16x8 bfr[4];
#pragma unroll
      for (int j = 0; j < 4; ++j)
        bfr[j] = *(const bf16x8*)(Bs + (br + j * 16) * BK + ((kk * 32 + kof) ^ rsw));
#pragma unroll
      for (int i = 0; i < 4; ++i) {
        bf16x8 af = *(const bf16x8*)(As + (ar + i * 16) * BK + ((kk * 32 + kof) ^ rsw));
#pragma unroll
        for (int j = 0; j < 4; ++j)
          acc[i][j] = __builtin_amdgcn_mfma_f32_16x16x32_bf16(af, bfr[j], acc[i][j], 0, 0, 0);
      }
    }
    asm volatile("" ::: "memory");
    __builtin_amdgcn_s_barrier();
    asm volatile("" ::: "memory");
    cur ^= 1;
  }

  const int crow = (lane >> 4) * 4;
  const int ccol = lane & 15;
#pragma unroll
  for (int i = 0; i < 4; ++i)
#pragma unroll
    for (int j = 0; j < 4; ++j) {
      size_t base = (size_t)(m0 + wr * 64 + i * 16 + crow) * N + (n0 + wc * 64 + j * 16 + ccol);
      if (BF16OUT) {
        unsigned short* C = (unsigned short*)Cv;
#pragma unroll
        for (int r = 0; r < 4; ++r) C[base + (size_t)r * N] = f2bf(acc[i][j][r]);
      } else {
        float* C = (float*)Cv;
#pragma unroll
        for (int r = 0; r < 4; ++r) C[base + (size_t)r * N] = acc[i][j][r];
      }
    }
}

// ---------------- conv1d + silu ----------------
__global__ __launch_bounds__(256) void k_conv_silu(const unsigned short* __restrict__ xb,
                                                   const unsigned short* __restrict__ wT,
                                                   const unsigned short* __restrict__ bT,
                                                   unsigned short* __restrict__ out) {
  long idx = (long)blockIdx.x * blockDim.x + threadIdx.x;
  if (idx >= (long)(NROWS / 4) * CG) return;
  int c8 = (int)(idx % CG);
  long rq = idx / CG;
  int l0 = (int)((rq & (SEQ / 4 - 1)) * 4);
  long brow = (rq >> 9) * (long)SEQ;
  int ch0 = c8 * 8;

  u16x8 wv[4];
#pragma unroll
  for (int w = 0; w < 4; ++w) wv[w] = *(const u16x8*)(wT + w * CONV_DIM + ch0);
  u16x8 bv = *(const u16x8*)(bT + ch0);

  u16x8 xr[7];
#pragma unroll
  for (int i = 0; i < 7; ++i) {
    int ls = l0 - 3 + i;
    if (ls >= 0) xr[i] = *(const u16x8*)(xb + (brow + ls) * (long)CONV_DIM + ch0);
    else { u16x8 z = {0, 0, 0, 0, 0, 0, 0, 0}; xr[i] = z; }
  }

#pragma unroll
  for (int r = 0; r < 4; ++r) {
    float acc[8];
#pragma unroll
    for (int e = 0; e < 8; ++e) acc[e] = bf2f(bv[e]);
#pragma unroll
    for (int w = 0; w < 4; ++w)
#pragma unroll
      for (int e = 0; e < 8; ++e) acc[e] += bf2f(xr[r + w][e]) * bf2f(wv[w][e]);
    u16x8 o;
#pragma unroll
    for (int e = 0; e < 8; ++e) o[e] = f2bf(acc[e] / (1.f + __expf(-acc[e])));
    *(u16x8*)(out + (brow + l0 + r) * (long)CONV_DIM + ch0) = o;
  }
}

// ---- CBT tiled layout: idx(l,s) = ((l>>4)*32 + (s>>3))*128 + (l&15)*8 + (s&7) ----
__global__ __launch_bounds__(256) void k_cbtt(const unsigned short* __restrict__ xbc, unsigned short* __restrict__ cbt_t) {
  const int bid = blockIdx.x;
  const int sp = bid & 3;
  const int bc = bid >> 2;
  const int b = bc >> 3, c = bc & 7;
  const int t = threadIdx.x;
  const int lane = t & 63;
  const int w = t >> 6;
  const int g = lane >> 4;
  __shared__ unsigned short Cs[256][72];
  __shared__ unsigned short Bs2[64][72];
  const long rowbase = (long)b * SEQ + c * CHUNK;
  f32x4 acc[4][4];
#pragma unroll
  for (int i = 0; i < 4; ++i)
#pragma unroll
    for (int j = 0; j < 4; ++j) { f32x4 z = {0.f, 0.f, 0.f, 0.f}; acc[i][j] = z; }

  for (int np = 0; np < 2; ++np) {
    __syncthreads();
    for (int i = t; i < 256 * 16; i += 256) {
      int row = i >> 4, c4 = (i & 15) * 4;
      ushort4 v = *(const ushort4*)(xbc + (rowbase + row) * (long)CONV_DIM + D_INNER + D_STATE + np * 64 + c4);
      *(ushort4*)&Cs[row][c4] = v;
    }
    for (int i = t; i < 64 * 16; i += 256) {
      int row = i >> 4, c4 = (i & 15) * 4;
      ushort4 v = *(const ushort4*)(xbc + (rowbase + sp * 64 + row) * (long)CONV_DIM + D_INNER + np * 64 + c4);
      *(ushort4*)&Bs2[row][c4] = v;
    }
    __syncthreads();
#pragma unroll
    for (int ks = 0; ks < 2; ++ks) {
      const int kofs = ks * 32 + g * 8;
      bf16x8 af[4], bfr[4];
#pragma unroll
      for (int i = 0; i < 4; ++i) af[i] = *(const bf16x8*)&Cs[w * 64 + i * 16 + (lane & 15)][kofs];
#pragma unroll
      for (int j = 0; j < 4; ++j) bfr[j] = *(const bf16x8*)&Bs2[j * 16 + (lane & 15)][kofs];
#pragma unroll
      for (int i = 0; i < 4; ++i)
#pragma unroll
        for (int j = 0; j < 4; ++j)
          acc[i][j] = __builtin_amdgcn_mfma_f32_16x16x32_bf16(af[i], bfr[j], acc[i][j], 0, 0, 0);
    }
  }
  unsigned short* ob = cbt_t + (long)bc * CHUNK * CHUNK;
#pragma unroll
  for (int i = 0; i < 4; ++i)
#pragma unroll
    for (int j = 0; j < 4; ++j) {
      int l0 = w * 64 + i * 16 + g * 4;
      int s = sp * 64 + j * 16 + (lane & 15);
#pragma unroll
      for (int r = 0; r < 4; ++r) {
        int l = l0 + r;
        ob[((long)(l >> 4) * 32 + (s >> 3)) * 128 + (l & 15) * 8 + (s & 7)] = f2bf(acc[i][j][r]);
      }
    }
}

// ---- states[n][p], MFMA, XOR-swizzled transpose staging ----
__global__ __launch_bounds__(256) void k_states(const unsigned short* __restrict__ xbc, const float* __restrict__ dt_t,
                                                const float* __restrict__ A_cum, float* __restrict__ states) {
  const int bid = blockIdx.x;
  const int h = bid & 63;
  const int bc = bid >> 6;
  const int b = bc >> 3, c = bc & 7;
  const int t = threadIdx.x;
  const int lane = t & 63;
  const int w = t >> 6;
  const int g = lane >> 4;
  __shared__ unsigned short BT[128][72];
  __shared__ unsigned short WXT[64][72];
  __shared__ float csL[256], dtL[256];
  const long rowbase = (long)b * SEQ + c * CHUNK;
  const long bh8 = ((long)(b * NHEADS + h)) * NCHUNK + c;
  const float* acum = A_cum + bh8 * CHUNK;
  if (t < 256) { csL[t] = acum[t]; dtL[t] = dt_t[((size_t)(b * NHEADS + h)) * SEQ + c * CHUNK + t]; }
  float cs_last = acum[255];
  f32x4 acc[2][4];
#pragma unroll
  for (int i = 0; i < 2; ++i)
#pragma unroll
    for (int j = 0; j < 4; ++j) { f32x4 z = {0.f, 0.f, 0.f, 0.f}; acc[i][j] = z; }

  for (int lp = 0; lp < 4; ++lp) {
    __syncthreads();
    for (int i = t; i < 64 * 32; i += 256) {
      int l = i >> 5, n4 = (i & 31) * 4;
      int sw = ((n4 >> 3) & 7) << 3;
      ushort4 v = *(const ushort4*)(xbc + (rowbase + lp * 64 + l) * (long)CONV_DIM + D_INNER + n4);
      BT[n4 + 0][l ^ sw] = v.x; BT[n4 + 1][l ^ sw] = v.y; BT[n4 + 2][l ^ sw] = v.z; BT[n4 + 3][l ^ sw] = v.w;
    }
    for (int i = t; i < 64 * 16; i += 256) {
      int l = i >> 4, p4 = (i & 15) * 4;
      int sw = ((p4 >> 3) & 7) << 3;
      int lg = lp * 64 + l;
      float wgt = __expf(cs_last - csL[lg]) * dtL[lg];
      ushort4 v = *(const ushort4*)(xbc + (rowbase + lg) * (long)CONV_DIM + h * HEADDIM + p4);
      WXT[p4 + 0][l ^ sw] = f2bf(bf2f(v.x) * wgt);
      WXT[p4 + 1][l ^ sw] = f2bf(bf2f(v.y) * wgt);
      WXT[p4 + 2][l ^ sw] = f2bf(bf2f(v.z) * wgt);
      WXT[p4 + 3][l ^ sw] = f2bf(bf2f(v.w) * wgt);
    }
    __syncthreads();
#pragma unroll
    for (int ks = 0; ks < 2; ++ks) {
      const int kofs = ks * 32 + g * 8;
      bf16x8 am[2], bp[4];
#pragma unroll
      for (int i = 0; i < 2; ++i) {
        int row = w * 32 + i * 16 + (lane & 15);
        am[i] = *(const bf16x8*)&BT[row][kofs ^ (((row >> 3) & 7) << 3)];
      }
#pragma unroll
      for (int j = 0; j < 4; ++j) {
        int row = j * 16 + (lane & 15);
        bp[j] = *(const bf16x8*)&WXT[row][kofs ^ (((row >> 3) & 7) << 3)];
      }
#pragma unroll
      for (int i = 0; i < 2; ++i)
#pragma unroll
        for (int j = 0; j < 4; ++j)
          acc[i][j] = __builtin_amdgcn_mfma_f32_16x16x32_bf16(am[i], bp[j], acc[i][j], 0, 0, 0);
    }
  }
  float* sp = states + ((long)bc * NHEADS + h) * (D_STATE * HEADDIM);
#pragma unroll
  for (int i = 0; i < 2; ++i)
#pragma unroll
    for (int j = 0; j < 4; ++j) {
      int n0 = w * 32 + i * 16 + g * 4;
      int p = j * 16 + (lane & 15);
#pragma unroll
      for (int r = 0; r < 4; ++r) sp[(long)(n0 + r) * HEADDIM + p] = acc[i][j][r];
    }
}

// ---------------- inter-chunk scan -> prev_states (bf16, [n][p]) ----------------
__global__ void k_scan(const float* __restrict__ states, const float* __restrict__ A_cum, unsigned short* __restrict__ psb) {
  long idx = (long)blockIdx.x * blockDim.x + threadIdx.x;
  if (idx >= (long)BATCH * NHEADS * D_STATE * HEADDIM) return;
  int p = idx & 63;
  int n = (int)((idx >> 6) & 127);
  long bh = idx >> 13;
  int h = (int)(bh & 63);
  int b = (int)(bh >> 6);
  float S = 0.f;
  for (int c = 0; c < NCHUNK; ++c) {
    long soff = (((long)(b * NCHUNK + c) * NHEADS + h) * (D_STATE * HEADDIM)) + (long)n * HEADDIM + p;
    psb[soff] = f2bf(S);
    float decay = __expf(A_cum[(bh * NCHUNK + c) * CHUNK + 255]);
    S = S * decay + states[soff];
  }
}

// ---- Y = Y_diag + Y_off + x*D: balanced waves, swizzled LDS, tiled cbt ----
__global__ __launch_bounds__(256) void k_y(const unsigned short* __restrict__ xbc, const float* __restrict__ dt_t,
                                           const float* __restrict__ A_cum, const unsigned short* __restrict__ cbt_t,
                                           const unsigned short* __restrict__ psb, const float* __restrict__ Dp,
                                           unsigned short* __restrict__ y) {
  const int bid = blockIdx.x;
  const int h = bid & 63;
  const int bc = bid >> 6;
  const int b = bc >> 3, c = bc & 7;
  const int t = threadIdx.x;
  const int lane = t & 63;
  const int w = t >> 6;
  const int g = lane >> 4;
  __shared__ unsigned short Abuf[256][56];
  __shared__ unsigned short Bbuf[64][72];
  __shared__ float csL[256], dtL[256], expL[256];
  const long rowbase = (long)b * SEQ + c * CHUNK;
  const long bh8 = ((long)(b * NHEADS + h)) * NCHUNK + c;
  const float* acum = A_cum + bh8 * CHUNK;
  if (t < 256) {
    float cv = acum[t];
    csL[t] = cv;
    expL[t] = __expf(cv);
    dtL[t] = dt_t[((size_t)(b * NHEADS + h)) * SEQ + c * CHUNK + t];
  }
  f32x4 acc[4][4];
#pragma unroll
  for (int i = 0; i < 4; ++i)
#pragma unroll
    for (int j = 0; j < 4; ++j) { f32x4 z = {0.f, 0.f, 0.f, 0.f}; acc[i][j] = z; }

  const unsigned short* psbase = psb + ((long)bc * NHEADS + h) * (D_STATE * HEADDIM);
  for (int np = 0; np < 4; ++np) {
    __syncthreads();
    for (int i = t; i < 256 * 8; i += 256) {
      int row = i >> 3, c4 = (i & 7) * 4;
      float el = expL[row];
      ushort4 v = *(const ushort4*)(xbc + (rowbase + row) * (long)CONV_DIM + D_INNER + D_STATE + np * 32 + c4);
      ushort4 o = make_ushort4(f2bf(bf2f(v.x) * el), f2bf(bf2f(v.y) * el), f2bf(bf2f(v.z) * el), f2bf(bf2f(v.w) * el));
      *(ushort4*)&Abuf[row][c4] = o;
    }
    for (int i = t; i < 512; i += 256) {
      int nl = i >> 4, p4 = (i & 15) * 4;
      int sw = ((p4 >> 3) & 7) << 3;
      ushort4 v = *(const ushort4*)(psbase + (long)(np * 32 + nl) * HEADDIM + p4);
      Bbuf[p4 + 0][nl ^ sw] = v.x; Bbuf[p4 + 1][nl ^ sw] = v.y;
      Bbuf[p4 + 2][nl ^ sw] = v.z; Bbuf[p4 + 3][nl ^ sw] = v.w;
    }
    __syncthreads();
    bf16x8 bfr[4];
#pragma unroll
    for (int j = 0; j < 4; ++j) {
      int row = j * 16 + (lane & 15);
      bfr[j] = *(const bf16x8*)&Bbuf[row][(g * 8) ^ (((row >> 3) & 7) << 3)];
    }
#pragma unroll
    for (int i = 0; i < 4; ++i) {
      bf16x8 af = *(const bf16x8*)&Abuf[(i * 4 + w) * 16 + (lane & 15)][g * 8];
#pragma unroll
      for (int j = 0; j < 4; ++j)
        acc[i][j] = __builtin_amdgcn_mfma_f32_16x16x32_bf16(af, bfr[j], acc[i][j], 0, 0, 0);
    }
  }

  const unsigned short* cbtb = cbt_t + (long)bc * CHUNK * CHUNK;
  for (int sp = 0; sp < 4; ++sp) {
    __syncthreads();
    for (int i = t; i < 512; i += 256) {
      int s = i >> 3, p0 = (i & 7) * 8;
      int sw = ((p0 >> 3) & 7) << 3;
      u16x8 v = *(const u16x8*)(xbc + (rowbase + sp * 64 + s) * (long)CONV_DIM + h * HEADDIM + p0);
#pragma unroll
      for (int e = 0; e < 8; ++e) Bbuf[p0 + e][s ^ sw] = v[e];
    }
    __syncthreads();
#pragma unroll
    for (int ks = 0; ks < 2; ++ks) {
      const int sb0 = sp * 64 + ks * 32;
      bf16x8 bfr[4];
#pragma unroll
      for (int j = 0; j < 4; ++j) {
        int row = j * 16 + (lane & 15);
        bfr[j] = *(const bf16x8*)&Bbuf[row][(ks * 32 + g * 8) ^ (((row >> 3) & 7) << 3)];
      }
      const int sbase = sb0 + g * 8;
#pragma unroll
      for (int i = 0; i < 4; ++i) {
        const int L0 = (i * 4 + w) * 16;
        if (sb0 > L0 + 15) continue;
        const int l = L0 + (lane & 15);
        u16x8 cv = *(const u16x8*)(cbtb + ((long)(L0 >> 4) * 32 + (sbase >> 3)) * 128 + (l & 15) * 8);
        const float cl = csL[l];
        bf16x8 af;
#pragma unroll
        for (int e = 0; e < 8; ++e) {
          int s = sbase + e;
          float val = (s <= l) ? bf2f(cv[e]) * __expf(cl - csL[s]) * dtL[s] : 0.f;
          af[e] = (short)f2bf(val);
        }
#pragma unroll
        for (int j = 0; j < 4; ++j)
          acc[i][j] = __builtin_amdgcn_mfma_f32_16x16x32_bf16(af, bfr[j], acc[i][j], 0, 0, 0);
      }
    }
  }

  const float Dh = Dp[h];
#pragma unroll
  for (int i = 0; i < 4; ++i) {
    int l0 = (i * 4 + w) * 16 + g * 4;
#pragma unroll
    for (int r = 0; r < 4; ++r) {
      long grow = rowbase + l0 + r;
      const unsigned short* xrow = xbc + grow * (long)CONV_DIM + h * HEADDIM;
      unsigned short* yrow = y + grow * (long)D_INNER + h * HEADDIM;
#pragma unroll
      for (int j = 0; j < 4; ++j) {
        int p = j * 16 + (lane & 15);
        yrow[p] = f2bf(acc[i][j][r] + bf2f(xrow[p]) * Dh);
      }
    }
  }
}

// ---------------- gated RMSNorm ----------------
__global__ __launch_bounds__(256) void k_norm(unsigned short* yz, const unsigned short* __restrict__ zb,
                                              const float* __restrict__ norm_w, unsigned short* out) {
  const int row = blockIdx.x;
  const int t = threadIdx.x;
  const unsigned short* yr = yz + (size_t)row * D_INNER;
  const unsigned short* zr = zb + (size_t)row * D_INNER;
  float yv[16];
  float ss = 0.f;
#pragma unroll
  for (int j = 0; j < 4; ++j) {
    int e = (t + j * 256) * 4;
    ushort4 yy = *(const ushort4*)(yr + e);
    ushort4 zz = *(const ushort4*)(zr + e);
    float z0 = bf2f(zz.x), z1 = bf2f(zz.y), z2 = bf2f(zz.z), z3 = bf2f(zz.w);
    float g0 = bf2f(yy.x) * z0 / (1.f + __expf(-z0));
    float g1 = bf2f(yy.y) * z1 / (1.f + __expf(-z1));
    float g2 = bf2f(yy.z) * z2 / (1.f + __expf(-z2));
    float g3 = bf2f(yy.w) * z3 / (1.f + __expf(-z3));
    ss += g0 * g0 + g1 * g1 + g2 * g2 + g3 * g3;
    yv[j * 4 + 0] = g0; yv[j * 4 + 1] = g1; yv[j * 4 + 2] = g2; yv[j * 4 + 3] = g3;
  }
#pragma unroll
  for (int off = 32; off > 0; off >>= 1) ss += __shfl_xor(ss, off);
  __shared__ float red[4];
  if ((t & 63) == 0) red[t >> 6] = ss;
  __syncthreads();
  float tot = red[0] + red[1] + red[2] + red[3];
  float scale = rsqrtf(tot / (float)D_INNER + EPSV);
  unsigned short* orow = out + (size_t)row * D_INNER;
#pragma unroll
  for (int j = 0; j < 4; ++j) {
    int e = (t + j * 256) * 4;
    float4 w = *(const float4*)(norm_w + e);
    ushort4 o = make_ushort4(f2bf(yv[j * 4 + 0] * scale * w.x), f2bf(yv[j * 4 + 1] * scale * w.y),
                             f2bf(yv[j * 4 + 2] * scale * w.z), f2bf(yv[j * 4 + 3] * scale * w.w));
    *(ushort4*)(orow + e) = o;
  }
}

extern "C" void kernel_launch(void* const* d_in, const int* in_sizes, int n_in,
                              void* d_out, int out_size, void* d_ws, size_t ws_size,
                              hipStream_t stream) {
  const float* u       = (const float*)d_in[0];
  const float* W_in    = (const float*)d_in[1];
  const float* conv_w  = (const float*)d_in[2];
  const float* conv_b  = (const float*)d_in[3];
  const float* dt_bias = (const float*)d_in[4];
  const float* A_log   = (const float*)d_in[5];
  const float* Dp      = (const float*)d_in[6];
  const float* norm_w  = (const float*)d_in[7];
  const float* W_out   = (const float*)d_in[8];
  float* out = (float*)d_out;

  char* ws = (char*)d_ws;
  size_t off = 0;
  auto alloc = [&](size_t bytes) { char* p = ws + off; off += (bytes + 255) & ~(size_t)255; return p; };
  unsigned short* ub   = (unsigned short*)alloc((size_t)NROWS * D_MODEL * 2);
  unsigned short* winb = (unsigned short*)alloc((size_t)D_IN_PROJ * D_MODEL * 2);
  unsigned short* zb   = (unsigned short*)alloc((size_t)NROWS * D_INNER * 2);
  unsigned short* xb   = (unsigned short*)alloc((size_t)NROWS * CONV_DIM * 2);
  unsigned short* xbcb = (unsigned short*)alloc((size_t)NROWS * CONV_DIM * 2);
  float* dtt  = (float*)alloc((size_t)BATCH * NHEADS * SEQ * 4);
  float* acum = (float*)alloc((size_t)BATCH * NHEADS * NCHUNK * CHUNK * 4);
  unsigned short* cwT = (unsigned short*)alloc((size_t)4 * CONV_DIM * 2);
  unsigned short* cbT = (unsigned short*)alloc((size_t)CONV_DIM * 2);
  unsigned short* whl = (unsigned short*)alloc((size_t)128 * D_MODEL * 2);
  float* PD = (float*)alloc((size_t)4 * BATCH * NHEADS * SEQ * 4);
  unsigned short* wob = ub;
  unsigned short* cbt = winb;
  unsigned short* psb = winb + (size_t)BATCH * NCHUNK * CHUNK * CHUNK + 1024;
  unsigned short* ulob = xbcb;
  unsigned short* yb = xb;
  float* states = (float*)d_out;

  if (off > ws_size) {
    k_sentinel<<<1, 64, 0, stream>>>(out);
    return;
  }

  k_prep<<<6673, 256, 0, stream>>>(u, ub, ulob, W_in, winb, whl, conv_w, conv_b, cwT, cbT);
  k_gemm8p<<<(NROWS / 256) * (D_INNER / 256), 512, 0, stream>>>(ub, winb, zb, NROWS, D_INNER, D_MODEL);
  k_gemm128<1><<<(NROWS / 128) * (CONV_DIM / 128), 256, 0, stream>>>(ub, winb + (size_t)D_INNER * D_MODEL, xb, NROWS, CONV_DIM, D_MODEL);
  k_dtm<<<256, 256, 0, stream>>>(ub, ulob, whl, PD);
  k_dtred<<<BATCH * NHEADS, 256, 0, stream>>>(PD, dt_bias, A_log, dtt, acum);
  k_conv_silu<<<(int)(((long)(NROWS / 4) * CG + 255) / 256), 256, 0, stream>>>(xb, cwT, cbT, xbcb);
  k_cbtt<<<BATCH * NCHUNK * 4, 256, 0, stream>>>(xbcb, cbt);
  k_states<<<BATCH * NCHUNK * NHEADS, 256, 0, stream>>>(xbcb, dtt, acum, states);
  k_scan<<<(BATCH * NHEADS * D_STATE * HEADDIM + 255) / 256, 256, 0, stream>>>(states, acum, psb);
  k_y<<<BATCH * NCHUNK * NHEADS, 256, 0, stream>>>(xbcb, dtt, acum, cbt, psb, Dp, yb);
  k_norm<<<NROWS, 256, 0, stream>>>(yb, zb, norm_w, yb);
  k_f32_to_bf16_v4<<<2048, 256, 0, stream>>>(W_out, wob, (long)D_MODEL * D_INNER / 4);
  k_gemm128<0><<<(NROWS / 128) * (D_MODEL / 128), 256, 0, stream>>>(yb, wob, out, NROWS, D_MODEL, D_INNER);
}

// Round 15
// 437.284 us; speedup vs baseline: 1.0546x; 1.0011x over previous
//
#include <hip/hip_runtime.h>

#define D_MODEL   2048
#define D_INNER   4096
#define HEADDIM   64
#define NHEADS    64
#define D_STATE   128
#define CHUNK     256
#define CONV_DIM  4352
#define D_IN_PROJ 8512
#define BATCH     2
#define SEQ       2048
#define NCHUNK    8
#define NROWS     4096
#define EPSV      1e-5f
#define CG        (CONV_DIM / 8)   // 544

typedef __attribute__((ext_vector_type(8))) short bf16x8;
typedef __attribute__((ext_vector_type(8))) unsigned short u16x8;
typedef __attribute__((ext_vector_type(4))) float f32x4;

#define AS1 __attribute__((address_space(1)))
#define AS3 __attribute__((address_space(3)))

#define BAR() do { asm volatile("" ::: "memory"); __builtin_amdgcn_s_barrier(); asm volatile("" ::: "memory"); } while (0)

__device__ __forceinline__ unsigned short f2bf(float f) {
  unsigned int x = __float_as_uint(f);
  unsigned int r = (x + 0x7fffu + ((x >> 16) & 1u)) >> 16;
  return (unsigned short)r;
}
__device__ __forceinline__ float bf2f(unsigned short u) {
  return __uint_as_float((unsigned int)u << 16);
}

__global__ void k_sentinel(float* out) { if (threadIdx.x == 0) out[0] = 1.0e6f; }

// ---------------- fused prep: usplit | W_in convert | wpack | conv pack ----------------
__global__ void k_prep(const float* __restrict__ u, unsigned short* __restrict__ uhi, unsigned short* __restrict__ ulo,
                       const float* __restrict__ W, unsigned short* __restrict__ winb, unsigned short* __restrict__ whl,
                       const float* __restrict__ cw, const float* __restrict__ cb,
                       unsigned short* __restrict__ cwT, unsigned short* __restrict__ cbT) {
  const int b = blockIdx.x;
  const int t = threadIdx.x;
  if (b < 2048) {
    const long n4 = (long)NROWS * D_MODEL / 4;
    for (long i = (long)b * 256 + t; i < n4; i += 2048L * 256) {
      float4 v = ((const float4*)u)[i];
      ushort4 h, l;
      h.x = f2bf(v.x); l.x = f2bf(v.x - bf2f(h.x));
      h.y = f2bf(v.y); l.y = f2bf(v.y - bf2f(h.y));
      h.z = f2bf(v.z); l.z = f2bf(v.z - bf2f(h.z));
      h.w = f2bf(v.w); l.w = f2bf(v.w - bf2f(h.w));
      ((ushort4*)uhi)[i] = h;
      ((ushort4*)ulo)[i] = l;
    }
  } else if (b < 6144) {
    const long n4 = (long)D_IN_PROJ * D_MODEL / 4;
    for (long i = (long)(b - 2048) * 256 + t; i < n4; i += 4096L * 256) {
      float4 v = ((const float4*)W)[i];
      ushort4 o = make_ushort4(f2bf(v.x), f2bf(v.y), f2bf(v.z), f2bf(v.w));
      ((ushort4*)winb)[i] = o;
    }
  } else if (b < 6656) {
    long i = (long)(b - 6144) * 256 + t;
    float v = W[(size_t)8448 * D_MODEL + i];
    unsigned short h = f2bf(v);
    whl[i] = h;
    whl[(size_t)64 * D_MODEL + i] = f2bf(v - bf2f(h));
  } else {
    int i = (b - 6656) * 256 + t;
    if (i < CONV_DIM) {
#pragma unroll
      for (int w = 0; w < 4; ++w) cwT[w * CONV_DIM + i] = f2bf(cw[i * 4 + w]);
      cbT[i] = f2bf(cb[i]);
    }
  }
}

// ---------------- W_out convert ----------------
__global__ void k_f32_to_bf16_v4(const float* __restrict__ in, unsigned short* __restrict__ out, long n4) {
  long i = (long)blockIdx.x * blockDim.x + threadIdx.x;
  long stride = (long)gridDim.x * blockDim.x;
  for (; i < n4; i += stride) {
    float4 v = ((const float4*)in)[i];
    ushort4 o = make_ushort4(f2bf(v.x), f2bf(v.y), f2bf(v.z), f2bf(v.w));
    ((ushort4*)out)[i] = o;
  }
}

// ---- dt split-bf16 MFMA, SPLIT-K=4 -> PD[ks][bh][l] (f32) ----
__global__ __launch_bounds__(256, 2) void k_dtm(const unsigned short* __restrict__ uhi,
                                                const unsigned short* __restrict__ ulo,
                                                const unsigned short* __restrict__ whl,
                                                float* __restrict__ PD) {
  __shared__ __align__(16) short lds[2][256 * 64];
  const int t = threadIdx.x;
  const int lane = t & 63;
  const int w = t >> 6;
  const int ks = (int)blockIdx.x & 3;
  const int m0 = ((int)blockIdx.x >> 2) * 64;
  const int kbase = ks * 512;

  f32x4 acc1[8], acc2[4];
#pragma unroll
  for (int j = 0; j < 8; ++j) { f32x4 z = {0.f, 0.f, 0.f, 0.f}; acc1[j] = z; }
#pragma unroll
  for (int j = 0; j < 4; ++j) { f32x4 z = {0.f, 0.f, 0.f, 0.f}; acc2[j] = z; }

  const int srow = t >> 3;
  const int schunk = (t & 7) ^ (srow & 7);
  const unsigned short* gU = uhi + (size_t)(m0 + srow) * D_MODEL + kbase + schunk * 8;
  const unsigned short* gL = ulo + (size_t)(m0 + srow) * D_MODEL + kbase + schunk * 8;
  const unsigned short* gW = whl + (size_t)srow * D_MODEL + kbase + schunk * 8;

  auto STAGE = [&](int buf, int kt) {
    char* d = (char*)&lds[buf][0] + t * 16;
#pragma unroll
    for (int ii = 0; ii < 2; ++ii)
      __builtin_amdgcn_global_load_lds((const AS1 void*)(gU + (size_t)ii * 32 * D_MODEL + (size_t)kt * 64),
                                       (AS3 void*)(d + ii * 4096), 16, 0, 0);
#pragma unroll
    for (int ii = 0; ii < 2; ++ii)
      __builtin_amdgcn_global_load_lds((const AS1 void*)(gL + (size_t)ii * 32 * D_MODEL + (size_t)kt * 64),
                                       (AS3 void*)(d + 8192 + ii * 4096), 16, 0, 0);
#pragma unroll
    for (int ii = 0; ii < 4; ++ii)
      __builtin_amdgcn_global_load_lds((const AS1 void*)(gW + (size_t)ii * 32 * D_MODEL + (size_t)kt * 64),
                                       (AS3 void*)(d + 16384 + ii * 4096), 16, 0, 0);
  };

  STAGE(0, 0);

  const int NT = 512 / 64;
  const int ar = w * 16 + (lane & 15);
  const int kof = (lane >> 4) * 8;
  const int rsw = (lane & 7) * 8;
  int cur = 0;
  for (int kt = 0; kt < NT; ++kt) {
    if (kt + 1 < NT) {
      STAGE(cur ^ 1, kt + 1);
      asm volatile("s_waitcnt vmcnt(8)" ::: "memory");
    } else {
      asm volatile("s_waitcnt vmcnt(0)" ::: "memory");
    }
    __builtin_amdgcn_s_barrier();
    asm volatile("" ::: "memory");
    const short* L = &lds[cur][0];
#pragma unroll
    for (int kk = 0; kk < 2; ++kk) {
      const int off = (kk * 32 + kof) ^ rsw;
      bf16x8 ah = *(const bf16x8*)(L + ar * 64 + off);
      bf16x8 al = *(const bf16x8*)(L + (64 + ar) * 64 + off);
#pragma unroll
      for (int j = 0; j < 8; ++j) {
        bf16x8 bj = *(const bf16x8*)(L + (128 + j * 16 + (lane & 15)) * 64 + off);
        acc1[j] = __builtin_amdgcn_mfma_f32_16x16x32_bf16(ah, bj, acc1[j], 0, 0, 0);
        if (j < 4) acc2[j] = __builtin_amdgcn_mfma_f32_16x16x32_bf16(al, bj, acc2[j], 0, 0, 0);
      }
    }
    asm volatile("" ::: "memory");
    __builtin_amdgcn_s_barrier();
    asm volatile("" ::: "memory");
    cur ^= 1;
  }

  const int crow = (lane >> 4) * 4;
  float* P = PD + (size_t)ks * BATCH * NHEADS * SEQ;
#pragma unroll
  for (int j = 0; j < 4; ++j) {
    int h = j * 16 + (lane & 15);
#pragma unroll
    for (int r = 0; r < 4; ++r) {
      int row = m0 + w * 16 + crow + r;
      float v = acc1[j][r] + acc1[j + 4][r] + acc2[j][r];
      P[(size_t)((row >> 11) * NHEADS + h) * SEQ + (row & 2047)] = v;
    }
  }
}

// ---- dt reduce + softplus -> dtt; fused per-chunk cumsum -> acum ----
__global__ __launch_bounds__(256) void k_dtred(const float* __restrict__ PD, const float* __restrict__ dt_bias,
                                               const float* __restrict__ A_log,
                                               float* __restrict__ dt_t, float* __restrict__ A_cum) {
  const int bh = blockIdx.x;
  const int h = bh & 63;
  const int t = threadIdx.x;
  const float bias = dt_bias[h];
  const float A = -__expf(A_log[h]);
  const size_t base = (size_t)bh * SEQ;
  const size_t pstride = (size_t)BATCH * NHEADS * SEQ;
  __shared__ float s[256];
  for (int c = 0; c < NCHUNK; ++c) {
    int l = c * CHUNK + t;
    float v = PD[base + l] + PD[pstride + base + l] + PD[2 * pstride + base + l] + PD[3 * pstride + base + l] + bias;
    float dtv = (v > 20.f) ? v : log1pf(expf(v));
    dt_t[base + l] = dtv;
    s[t] = dtv * A;
    __syncthreads();
    for (int off = 1; off < 256; off <<= 1) {
      float x = (t >= off) ? s[t - off] : 0.f;
      __syncthreads();
      s[t] += x;
      __syncthreads();
    }
    A_cum[((size_t)bh * NCHUNK + c) * CHUNK + t] = s[t];
    __syncthreads();
  }
}

// ---- 256x256 BK=64 8-phase GEMM (T2+T3+T4+T5), grouped-raster XCD swizzle ----
__global__ __launch_bounds__(512, 2) void k_gemm8p(const unsigned short* __restrict__ A,
                                                   const unsigned short* __restrict__ B,
                                                   unsigned short* __restrict__ C, int M, int N, int K) {
  __shared__ __align__(16) short lds[2][32768];
  const int t = threadIdx.x;
  const int lane = t & 63;
  const int wid = t >> 6;
  const int wr = wid >> 2;
  const int wc = wid & 3;
  const int ntx = N / 256;
  const int nwg = (int)gridDim.x;
  const int bid = (int)blockIdx.x;
  const int swz = (bid & 7) * (nwg >> 3) + (bid >> 3);
  const int grp = ntx << 3;
  const int gid = swz / grp;
  const int rem = swz - gid * grp;
  const int m0 = ((gid << 3) + (rem & 7)) * 256;
  const int n0 = (rem >> 3) * 256;

  f32x4 acc[8][4];
#pragma unroll
  for (int i = 0; i < 8; ++i)
#pragma unroll
    for (int j = 0; j < 4; ++j) { f32x4 z = {0.f, 0.f, 0.f, 0.f}; acc[i][j] = z; }

  const int srow = t >> 3;
  const int schunk = (t & 7) ^ (srow & 7);
  const unsigned short* gA = A + (size_t)(m0 + srow) * K + schunk * 8;
  const unsigned short* gB = B + (size_t)(n0 + srow) * K + schunk * 8;

  auto STAGE_HALF = [&](int buf, int kt, int which) {
    const unsigned short* g = (which < 2 ? gA : gB) + (size_t)(which & 1) * 128 * K + (size_t)kt * 64;
    char* d = (char*)lds + buf * 65536 + which * 16384 + t * 16;
    __builtin_amdgcn_global_load_lds((const AS1 void*)g, (AS3 void*)d, 16, 0, 0);
    __builtin_amdgcn_global_load_lds((const AS1 void*)(g + (size_t)64 * K), (AS3 void*)(d + 8192), 16, 0, 0);
  };

  const int NT = K / 64;
  STAGE_HALF(0, 0, 0); STAGE_HALF(0, 0, 1); STAGE_HALF(0, 0, 2); STAGE_HALF(0, 0, 3);
  STAGE_HALF(1, 1, 2); STAGE_HALF(1, 1, 0); STAGE_HALF(1, 1, 1);
  asm volatile("s_waitcnt vmcnt(6)" ::: "memory");
  BAR();

  const int ar = wr * 128 + (lane & 15);
  const int br = wc * 64 + (lane & 15);
  const int kof = (lane >> 4) * 8;
  const int rsw = (lane & 7) * 8;

  for (int kt = 0; kt < NT; ++kt) {
    const int buf = kt & 1;
    const short* As = &lds[buf][0];
    const short* Bs = &lds[buf][16384];
    const bool s1 = (kt + 1 < NT);
    const bool s2 = (kt + 2 < NT);
    bf16x8 aLo[4][2], aHi[4][2], bLo[2][2], bHi[2][2];

#pragma unroll
    for (int i = 0; i < 4; ++i)
#pragma unroll
      for (int k = 0; k < 2; ++k) aLo[i][k] = *(const bf16x8*)(As + (ar + i * 16) * 64 + ((k * 32 + kof) ^ rsw));
#pragma unroll
    for (int j = 0; j < 2; ++j)
#pragma unroll
      for (int k = 0; k < 2; ++k) bLo[j][k] = *(const bf16x8*)(Bs + (br + j * 16) * 64 + ((k * 32 + kof) ^ rsw));
    if (s1) STAGE_HALF(buf ^ 1, kt + 1, 3);
    BAR();
    __builtin_amdgcn_s_setprio(1);
#pragma unroll
    for (int k = 0; k < 2; ++k)
#pragma unroll
      for (int i = 0; i < 4; ++i)
#pragma unroll
        for (int j = 0; j < 2; ++j)
          acc[i][j] = __builtin_amdgcn_mfma_f32_16x16x32_bf16(aLo[i][k], bLo[j][k], acc[i][j], 0, 0, 0);
    __builtin_amdgcn_s_setprio(0);
    BAR();

#pragma unroll
    for (int j = 0; j < 2; ++j)
#pragma unroll
      for (int k = 0; k < 2; ++k) bHi[j][k] = *(const bf16x8*)(Bs + (br + (j + 2) * 16) * 64 + ((k * 32 + kof) ^ rsw));
    BAR();
    __builtin_amdgcn_s_setprio(1);
#pragma unroll
    for (int k = 0; k < 2; ++k)
#pragma unroll
      for (int i = 0; i < 4; ++i)
#pragma unroll
        for (int j = 0; j < 2; ++j)
          acc[i][j + 2] = __builtin_amdgcn_mfma_f32_16x16x32_bf16(aLo[i][k], bHi[j][k], acc[i][j + 2], 0, 0, 0);
    __builtin_amdgcn_s_setprio(0);
    BAR();

#pragma unroll
    for (int i = 0; i < 4; ++i)
#pragma unroll
      for (int k = 0; k < 2; ++k) aHi[i][k] = *(const bf16x8*)(As + (ar + (i + 4) * 16) * 64 + ((k * 32 + kof) ^ rsw));
    if (s2) STAGE_HALF(buf, kt + 2, 2);
    BAR();
    __builtin_amdgcn_s_setprio(1);
#pragma unroll
    for (int k = 0; k < 2; ++k)
#pragma unroll
      for (int i = 0; i < 4; ++i)
#pragma unroll
        for (int j = 0; j < 2; ++j)
          acc[i + 4][j] = __builtin_amdgcn_mfma_f32_16x16x32_bf16(aHi[i][k], bLo[j][k], acc[i + 4][j], 0, 0, 0);
    __builtin_amdgcn_s_setprio(0);
    BAR();

    if (s2) { STAGE_HALF(buf, kt + 2, 0); STAGE_HALF(buf, kt + 2, 1); }
    if (s2) { asm volatile("s_waitcnt vmcnt(6)" ::: "memory"); }
    else    { asm volatile("s_waitcnt vmcnt(0)" ::: "memory"); }
    BAR();
    __builtin_amdgcn_s_setprio(1);
#pragma unroll
    for (int k = 0; k < 2; ++k)
#pragma unroll
      for (int i = 0; i < 4; ++i)
#pragma unroll
        for (int j = 0; j < 2; ++j)
          acc[i + 4][j + 2] = __builtin_amdgcn_mfma_f32_16x16x32_bf16(aHi[i][k], bHi[j][k], acc[i + 4][j + 2], 0, 0, 0);
    __builtin_amdgcn_s_setprio(0);
    BAR();
  }

  const int crow = (lane >> 4) * 4;
  const int ccol = lane & 15;
#pragma unroll
  for (int i = 0; i < 8; ++i)
#pragma unroll
    for (int j = 0; j < 4; ++j) {
      size_t base = (size_t)(m0 + wr * 128 + i * 16 + crow) * N + (n0 + wc * 64 + j * 16 + ccol);
#pragma unroll
      for (int r = 0; r < 4; ++r) C[base + (size_t)r * N] = f2bf(acc[i][j][r]);
    }
}

// ---- 128x128 BK=64 double-buffered GEMM, counted vmcnt, GM=8 grouped raster ----
template <int BF16OUT>
__global__ __launch_bounds__(256, 2) void k_gemm128(const unsigned short* __restrict__ A,
                                                    const unsigned short* __restrict__ B,
                                                    void* __restrict__ Cv, int M, int N, int K) {
  constexpr int BK = 64;
  __shared__ __align__(16) short lds[2][256 * BK];
  const int t = threadIdx.x;
  const int lane = t & 63;
  const int wid = t >> 6;
  const int wr = wid >> 1;
  const int wc = wid & 1;
  const int ntx = N / 128;
  const int nwg = (int)gridDim.x;
  const int bid = (int)blockIdx.x;
  const int swz = (bid & 7) * (nwg >> 3) + (bid >> 3);
  const int grp = ntx << 3;            // requires nwg % grp == 0
  const int gid = swz / grp;
  const int rem = swz - gid * grp;
  const int m0 = ((gid << 3) + (rem & 7)) * 128;
  const int n0 = (rem >> 3) * 128;

  f32x4 acc[4][4];
#pragma unroll
  for (int i = 0; i < 4; ++i)
#pragma unroll
    for (int j = 0; j < 4; ++j) { f32x4 z = {0.f, 0.f, 0.f, 0.f}; acc[i][j] = z; }

  const int srow = t >> 3;
  const int schunk = (t & 7) ^ (srow & 7);
  const unsigned short* gA = A + (size_t)(m0 + srow) * K + schunk * 8;
  const unsigned short* gB = B + (size_t)(n0 + srow) * K + schunk * 8;

  auto STAGE = [&](int buf, int kt) {
    char* dA = (char*)&lds[buf][0] + t * 16;
    char* dB = (char*)&lds[buf][128 * BK] + t * 16;
#pragma unroll
    for (int ii = 0; ii < 4; ++ii)
      __builtin_amdgcn_global_load_lds((const AS1 void*)(gA + (size_t)ii * 32 * K + kt * BK),
                                       (AS3 void*)(dA + ii * 4096), 16, 0, 0);
#pragma unroll
    for (int ii = 0; ii < 4; ++ii)
      __builtin_amdgcn_global_load_lds((const AS1 void*)(gB + (size_t)ii * 32 * K + kt * BK),
                                       (AS3 void*)(dB + ii * 4096), 16, 0, 0);
  };

  STAGE(0, 0);

  const int NT = K / BK;
  const int ar = wr * 64 + (lane & 15);
  const int br = wc * 64 + (lane & 15);
  const int kof = (lane >> 4) * 8;
  const int rsw = (lane & 7) * 8;
  int cur = 0;
  for (int kt = 0; kt < NT; ++kt) {
    if (kt + 1 < NT) {
      STAGE(cur ^ 1, kt + 1);
      asm volatile("s_waitcnt vmcnt(8)" ::: "memory");
    } else {
      asm volatile("s_waitcnt vmcnt(0)" ::: "memory");
    }
    __builtin_amdgcn_s_barrier();
    asm volatile("" ::: "memory");
    const short* As = &lds[cur][0];
    const short* Bs = &lds[cur][128 * BK];
#pragma unroll
    for (int kk = 0; kk < 2; ++kk) {
      bf16x8 bfr[4];
#pragma unroll
      for (int j = 0; j < 4; ++j)
        bfr[j] = *(const bf16x8*)(Bs + (br + j * 16) * BK + ((kk * 32 + kof) ^ rsw));
#pragma unroll
      for (int i = 0; i < 4; ++i) {
        bf16x8 af = *(const bf16x8*)(As + (ar + i * 16) * BK + ((kk * 32 + kof) ^ rsw));
#pragma unroll
        for (int j = 0; j < 4; ++j)
          acc[i][j] = __builtin_amdgcn_mfma_f32_16x16x32_bf16(af, bfr[j], acc[i][j], 0, 0, 0);
      }
    }
    asm volatile("" ::: "memory");
    __builtin_amdgcn_s_barrier();
    asm volatile("" ::: "memory");
    cur ^= 1;
  }

  const int crow = (lane >> 4) * 4;
  const int ccol = lane & 15;
#pragma unroll
  for (int i = 0; i < 4; ++i)
#pragma unroll
    for (int j = 0; j < 4; ++j) {
      size_t base = (size_t)(m0 + wr * 64 + i * 16 + crow) * N + (n0 + wc * 64 + j * 16 + ccol);
      if (BF16OUT) {
        unsigned short* C = (unsigned short*)Cv;
#pragma unroll
        for (int r = 0; r < 4; ++r) C[base + (size_t)r * N] = f2bf(acc[i][j][r]);
      } else {
        float* C = (float*)Cv;
#pragma unroll
        for (int r = 0; r < 4; ++r) C[base + (size_t)r * N] = acc[i][j][r];
      }
    }
}

// ---------------- conv1d + silu ----------------
__global__ __launch_bounds__(256) void k_conv_silu(const unsigned short* __restrict__ xb,
                                                   const unsigned short* __restrict__ wT,
                                                   const unsigned short* __restrict__ bT,
                                                   unsigned short* __restrict__ out) {
  long idx = (long)blockIdx.x * blockDim.x + threadIdx.x;
  if (idx >= (long)(NROWS / 4) * CG) return;
  int c8 = (int)(idx % CG);
  long rq = idx / CG;
  int l0 = (int)((rq & (SEQ / 4 - 1)) * 4);
  long brow = (rq >> 9) * (long)SEQ;
  int ch0 = c8 * 8;

  u16x8 wv[4];
#pragma unroll
  for (int w = 0; w < 4; ++w) wv[w] = *(const u16x8*)(wT + w * CONV_DIM + ch0);
  u16x8 bv = *(const u16x8*)(bT + ch0);

  u16x8 xr[7];
#pragma unroll
  for (int i = 0; i < 7; ++i) {
    int ls = l0 - 3 + i;
    if (ls >= 0) xr[i] = *(const u16x8*)(xb + (brow + ls) * (long)CONV_DIM + ch0);
    else { u16x8 z = {0, 0, 0, 0, 0, 0, 0, 0}; xr[i] = z; }
  }

#pragma unroll
  for (int r = 0; r < 4; ++r) {
    float acc[8];
#pragma unroll
    for (int e = 0; e < 8; ++e) acc[e] = bf2f(bv[e]);
#pragma unroll
    for (int w = 0; w < 4; ++w)
#pragma unroll
      for (int e = 0; e < 8; ++e) acc[e] += bf2f(xr[r + w][e]) * bf2f(wv[w][e]);
    u16x8 o;
#pragma unroll
    for (int e = 0; e < 8; ++e) o[e] = f2bf(acc[e] / (1.f + __expf(-acc[e])));
    *(u16x8*)(out + (brow + l0 + r) * (long)CONV_DIM + ch0) = o;
  }
}

// ---- CBT tiled layout: idx(l,s) = ((l>>4)*32 + (s>>3))*128 + (l&15)*8 + (s&7) ----
__global__ __launch_bounds__(256) void k_cbtt(const unsigned short* __restrict__ xbc, unsigned short* __restrict__ cbt_t) {
  const int bid = blockIdx.x;
  const int sp = bid & 3;
  const int bc = bid >> 2;
  const int b = bc >> 3, c = bc & 7;
  const int t = threadIdx.x;
  const int lane = t & 63;
  const int w = t >> 6;
  const int g = lane >> 4;
  __shared__ unsigned short Cs[256][72];
  __shared__ unsigned short Bs2[64][72];
  const long rowbase = (long)b * SEQ + c * CHUNK;
  f32x4 acc[4][4];
#pragma unroll
  for (int i = 0; i < 4; ++i)
#pragma unroll
    for (int j = 0; j < 4; ++j) { f32x4 z = {0.f, 0.f, 0.f, 0.f}; acc[i][j] = z; }

  for (int np = 0; np < 2; ++np) {
    __syncthreads();
    for (int i = t; i < 256 * 16; i += 256) {
      int row = i >> 4, c4 = (i & 15) * 4;
      ushort4 v = *(const ushort4*)(xbc + (rowbase + row) * (long)CONV_DIM + D_INNER + D_STATE + np * 64 + c4);
      *(ushort4*)&Cs[row][c4] = v;
    }
    for (int i = t; i < 64 * 16; i += 256) {
      int row = i >> 4, c4 = (i & 15) * 4;
      ushort4 v = *(const ushort4*)(xbc + (rowbase + sp * 64 + row) * (long)CONV_DIM + D_INNER + np * 64 + c4);
      *(ushort4*)&Bs2[row][c4] = v;
    }
    __syncthreads();
#pragma unroll
    for (int ks = 0; ks < 2; ++ks) {
      const int kofs = ks * 32 + g * 8;
      bf16x8 af[4], bfr[4];
#pragma unroll
      for (int i = 0; i < 4; ++i) af[i] = *(const bf16x8*)&Cs[w * 64 + i * 16 + (lane & 15)][kofs];
#pragma unroll
      for (int j = 0; j < 4; ++j) bfr[j] = *(const bf16x8*)&Bs2[j * 16 + (lane & 15)][kofs];
#pragma unroll
      for (int i = 0; i < 4; ++i)
#pragma unroll
        for (int j = 0; j < 4; ++j)
          acc[i][j] = __builtin_amdgcn_mfma_f32_16x16x32_bf16(af[i], bfr[j], acc[i][j], 0, 0, 0);
    }
  }
  unsigned short* ob = cbt_t + (long)bc * CHUNK * CHUNK;
#pragma unroll
  for (int i = 0; i < 4; ++i)
#pragma unroll
    for (int j = 0; j < 4; ++j) {
      int l0 = w * 64 + i * 16 + g * 4;
      int s = sp * 64 + j * 16 + (lane & 15);
#pragma unroll
      for (int r = 0; r < 4; ++r) {
        int l = l0 + r;
        ob[((long)(l >> 4) * 32 + (s >> 3)) * 128 + (l & 15) * 8 + (s & 7)] = f2bf(acc[i][j][r]);
      }
    }
}

// ---- states[n][p], MFMA, XOR-swizzled transpose staging; safe factored decay (arg <= 0) ----
__global__ __launch_bounds__(256) void k_states(const unsigned short* __restrict__ xbc, const float* __restrict__ dt_t,
                                                const float* __restrict__ A_cum, float* __restrict__ states) {
  const int bid = blockIdx.x;
  const int h = bid & 63;
  const int bc = bid >> 6;
  const int b = bc >> 3, c = bc & 7;
  const int t = threadIdx.x;
  const int lane = t & 63;
  const int w = t >> 6;
  const int g = lane >> 4;
  __shared__ unsigned short BT[128][72];
  __shared__ unsigned short WXT[64][72];
  __shared__ float wdt[256];     // exp(cs_last - cs_l) * dt_l  (argument <= 0 always)
  const long rowbase = (long)b * SEQ + c * CHUNK;
  const long bh8 = ((long)(b * NHEADS + h)) * NCHUNK + c;
  const float* acum = A_cum + bh8 * CHUNK;
  {
    float cs_last = acum[255];
    float cv = acum[t];
    wdt[t] = __expf(cs_last - cv) * dt_t[((size_t)(b * NHEADS + h)) * SEQ + c * CHUNK + t];
  }
  f32x4 acc[2][4];
#pragma unroll
  for (int i = 0; i < 2; ++i)
#pragma unroll
    for (int j = 0; j < 4; ++j) { f32x4 z = {0.f, 0.f, 0.f, 0.f}; acc[i][j] = z; }

  for (int lp = 0; lp < 4; ++lp) {
    __syncthreads();
    for (int i = t; i < 64 * 32; i += 256) {
      int l = i >> 5, n4 = (i & 31) * 4;
      int sw = ((n4 >> 3) & 7) << 3;
      ushort4 v = *(const ushort4*)(xbc + (rowbase + lp * 64 + l) * (long)CONV_DIM + D_INNER + n4);
      BT[n4 + 0][l ^ sw] = v.x; BT[n4 + 1][l ^ sw] = v.y; BT[n4 + 2][l ^ sw] = v.z; BT[n4 + 3][l ^ sw] = v.w;
    }
    for (int i = t; i < 64 * 16; i += 256) {
      int l = i >> 4, p4 = (i & 15) * 4;
      int sw = ((p4 >> 3) & 7) << 3;
      int lg = lp * 64 + l;
      float wgt = wdt[lg];
      ushort4 v = *(const ushort4*)(xbc + (rowbase + lg) * (long)CONV_DIM + h * HEADDIM + p4);
      WXT[p4 + 0][l ^ sw] = f2bf(bf2f(v.x) * wgt);
      WXT[p4 + 1][l ^ sw] = f2bf(bf2f(v.y) * wgt);
      WXT[p4 + 2][l ^ sw] = f2bf(bf2f(v.z) * wgt);
      WXT[p4 + 3][l ^ sw] = f2bf(bf2f(v.w) * wgt);
    }
    __syncthreads();
#pragma unroll
    for (int ks = 0; ks < 2; ++ks) {
      const int kofs = ks * 32 + g * 8;
      bf16x8 am[2], bp[4];
#pragma unroll
      for (int i = 0; i < 2; ++i) {
        int row = w * 32 + i * 16 + (lane & 15);
        am[i] = *(const bf16x8*)&BT[row][kofs ^ (((row >> 3) & 7) << 3)];
      }
#pragma unroll
      for (int j = 0; j < 4; ++j) {
        int row = j * 16 + (lane & 15);
        bp[j] = *(const bf16x8*)&WXT[row][kofs ^ (((row >> 3) & 7) << 3)];
      }
#pragma unroll
      for (int i = 0; i < 2; ++i)
#pragma unroll
        for (int j = 0; j < 4; ++j)
          acc[i][j] = __builtin_amdgcn_mfma_f32_16x16x32_bf16(am[i], bp[j], acc[i][j], 0, 0, 0);
    }
  }
  float* sp = states + ((long)bc * NHEADS + h) * (D_STATE * HEADDIM);
#pragma unroll
  for (int i = 0; i < 2; ++i)
#pragma unroll
    for (int j = 0; j < 4; ++j) {
      int n0 = w * 32 + i * 16 + g * 4;
      int p = j * 16 + (lane & 15);
#pragma unroll
      for (int r = 0; r < 4; ++r) sp[(long)(n0 + r) * HEADDIM + p] = acc[i][j][r];
    }
}

// ---------------- inter-chunk scan -> prev_states (bf16, [n][p]) ----------------
__global__ void k_scan(const float* __restrict__ states, const float* __restrict__ A_cum, unsigned short* __restrict__ psb) {
  long idx = (long)blockIdx.x * blockDim.x + threadIdx.x;
  if (idx >= (long)BATCH * NHEADS * D_STATE * HEADDIM) return;
  int p = idx & 63;
  int n = (int)((idx >> 6) & 127);
  long bh = idx >> 13;
  int h = (int)(bh & 63);
  int b = (int)(bh >> 6);
  float S = 0.f;
  for (int c = 0; c < NCHUNK; ++c) {
    long soff = (((long)(b * NCHUNK + c) * NHEADS + h) * (D_STATE * HEADDIM)) + (long)n * HEADDIM + p;
    psb[soff] = f2bf(S);
    float decay = __expf(A_cum[(bh * NCHUNK + c) * CHUNK + 255]);
    S = S * decay + states[soff];
  }
}

// ---- Y = Y_diag + Y_off + x*D: balanced waves, swizzled LDS, tiled cbt (direct safe exp) ----
__global__ __launch_bounds__(256) void k_y(const unsigned short* __restrict__ xbc, const float* __restrict__ dt_t,
                                           const float* __restrict__ A_cum, const unsigned short* __restrict__ cbt_t,
                                           const unsigned short* __restrict__ psb, const float* __restrict__ Dp,
                                           unsigned short* __restrict__ y) {
  const int bid = blockIdx.x;
  const int h = bid & 63;
  const int bc = bid >> 6;
  const int b = bc >> 3, c = bc & 7;
  const int t = threadIdx.x;
  const int lane = t & 63;
  const int w = t >> 6;
  const int g = lane >> 4;
  __shared__ unsigned short Abuf[256][56];
  __shared__ unsigned short Bbuf[64][72];
  __shared__ float csL[256], dtL[256], expL[256];
  const long rowbase = (long)b * SEQ + c * CHUNK;
  const long bh8 = ((long)(b * NHEADS + h)) * NCHUNK + c;
  const float* acum = A_cum + bh8 * CHUNK;
  if (t < 256) {
    float cv = acum[t];
    csL[t] = cv;
    expL[t] = __expf(cv);
    dtL[t] = dt_t[((size_t)(b * NHEADS + h)) * SEQ + c * CHUNK + t];
  }
  f32x4 acc[4][4];
#pragma unroll
  for (int i = 0; i < 4; ++i)
#pragma unroll
    for (int j = 0; j < 4; ++j) { f32x4 z = {0.f, 0.f, 0.f, 0.f}; acc[i][j] = z; }

  const unsigned short* psbase = psb + ((long)bc * NHEADS + h) * (D_STATE * HEADDIM);
  for (int np = 0; np < 4; ++np) {
    __syncthreads();
    for (int i = t; i < 256 * 8; i += 256) {
      int row = i >> 3, c4 = (i & 7) * 4;
      float el = expL[row];
      ushort4 v = *(const ushort4*)(xbc + (rowbase + row) * (long)CONV_DIM + D_INNER + D_STATE + np * 32 + c4);
      ushort4 o = make_ushort4(f2bf(bf2f(v.x) * el), f2bf(bf2f(v.y) * el), f2bf(bf2f(v.z) * el), f2bf(bf2f(v.w) * el));
      *(ushort4*)&Abuf[row][c4] = o;
    }
    for (int i = t; i < 512; i += 256) {
      int nl = i >> 4, p4 = (i & 15) * 4;
      int sw = ((p4 >> 3) & 7) << 3;
      ushort4 v = *(const ushort4*)(psbase + (long)(np * 32 + nl) * HEADDIM + p4);
      Bbuf[p4 + 0][nl ^ sw] = v.x; Bbuf[p4 + 1][nl ^ sw] = v.y;
      Bbuf[p4 + 2][nl ^ sw] = v.z; Bbuf[p4 + 3][nl ^ sw] = v.w;
    }
    __syncthreads();
    bf16x8 bfr[4];
#pragma unroll
    for (int j = 0; j < 4; ++j) {
      int row = j * 16 + (lane & 15);
      bfr[j] = *(const bf16x8*)&Bbuf[row][(g * 8) ^ (((row >> 3) & 7) << 3)];
    }
#pragma unroll
    for (int i = 0; i < 4; ++i) {
      bf16x8 af = *(const bf16x8*)&Abuf[(i * 4 + w) * 16 + (lane & 15)][g * 8];
#pragma unroll
      for (int j = 0; j < 4; ++j)
        acc[i][j] = __builtin_amdgcn_mfma_f32_16x16x32_bf16(af, bfr[j], acc[i][j], 0, 0, 0);
    }
  }

  const unsigned short* cbtb = cbt_t + (long)bc * CHUNK * CHUNK;
  for (int sp = 0; sp < 4; ++sp) {
    __syncthreads();
    for (int i = t; i < 512; i += 256) {
      int s = i >> 3, p0 = (i & 7) * 8;
      int sw = ((p0 >> 3) & 7) << 3;
      u16x8 v = *(const u16x8*)(xbc + (rowbase + sp * 64 + s) * (long)CONV_DIM + h * HEADDIM + p0);
#pragma unroll
      for (int e = 0; e < 8; ++e) Bbuf[p0 + e][s ^ sw] = v[e];
    }
    __syncthreads();
#pragma unroll
    for (int ks = 0; ks < 2; ++ks) {
      const int sb0 = sp * 64 + ks * 32;
      bf16x8 bfr[4];
#pragma unroll
      for (int j = 0; j < 4; ++j) {
        int row = j * 16 + (lane & 15);
        bfr[j] = *(const bf16x8*)&Bbuf[row][(ks * 32 + g * 8) ^ (((row >> 3) & 7) << 3)];
      }
      const int sbase = sb0 + g * 8;
#pragma unroll
      for (int i = 0; i < 4; ++i) {
        const int L0 = (i * 4 + w) * 16;
        if (sb0 > L0 + 15) continue;
        const int l = L0 + (lane & 15);
        u16x8 cv = *(const u16x8*)(cbtb + ((long)(L0 >> 4) * 32 + (sbase >> 3)) * 128 + (l & 15) * 8);
        const float cl = csL[l];
        bf16x8 af;
#pragma unroll
        for (int e = 0; e < 8; ++e) {
          int s = sbase + e;
          float val = (s <= l) ? bf2f(cv[e]) * __expf(cl - csL[s]) * dtL[s] : 0.f;
          af[e] = (short)f2bf(val);
        }
#pragma unroll
        for (int j = 0; j < 4; ++j)
          acc[i][j] = __builtin_amdgcn_mfma_f32_16x16x32_bf16(af, bfr[j], acc[i][j], 0, 0, 0);
      }
    }
  }

  const float Dh = Dp[h];
#pragma unroll
  for (int i = 0; i < 4; ++i) {
    int l0 = (i * 4 + w) * 16 + g * 4;
#pragma unroll
    for (int r = 0; r < 4; ++r) {
      long grow = rowbase + l0 + r;
      const unsigned short* xrow = xbc + grow * (long)CONV_DIM + h * HEADDIM;
      unsigned short* yrow = y + grow * (long)D_INNER + h * HEADDIM;
#pragma unroll
      for (int j = 0; j < 4; ++j) {
        int p = j * 16 + (lane & 15);
        yrow[p] = f2bf(acc[i][j][r] + bf2f(xrow[p]) * Dh);
      }
    }
  }
}

// ---------------- gated RMSNorm ----------------
__global__ __launch_bounds__(256) void k_norm(unsigned short* yz, const unsigned short* __restrict__ zb,
                                              const float* __restrict__ norm_w, unsigned short* out) {
  const int row = blockIdx.x;
  const int t = threadIdx.x;
  const unsigned short* yr = yz + (size_t)row * D_INNER;
  const unsigned short* zr = zb + (size_t)row * D_INNER;
  float yv[16];
  float ss = 0.f;
#pragma unroll
  for (int j = 0; j < 4; ++j) {
    int e = (t + j * 256) * 4;
    ushort4 yy = *(const ushort4*)(yr + e);
    ushort4 zz = *(const ushort4*)(zr + e);
    float z0 = bf2f(zz.x), z1 = bf2f(zz.y), z2 = bf2f(zz.z), z3 = bf2f(zz.w);
    float g0 = bf2f(yy.x) * z0 / (1.f + __expf(-z0));
    float g1 = bf2f(yy.y) * z1 / (1.f + __expf(-z1));
    float g2 = bf2f(yy.z) * z2 / (1.f + __expf(-z2));
    float g3 = bf2f(yy.w) * z3 / (1.f + __expf(-z3));
    ss += g0 * g0 + g1 * g1 + g2 * g2 + g3 * g3;
    yv[j * 4 + 0] = g0; yv[j * 4 + 1] = g1; yv[j * 4 + 2] = g2; yv[j * 4 + 3] = g3;
  }
#pragma unroll
  for (int off = 32; off > 0; off >>= 1) ss += __shfl_xor(ss, off);
  __shared__ float red[4];
  if ((t & 63) == 0) red[t >> 6] = ss;
  __syncthreads();
  float tot = red[0] + red[1] + red[2] + red[3];
  float scale = rsqrtf(tot / (float)D_INNER + EPSV);
  unsigned short* orow = out + (size_t)row * D_INNER;
#pragma unroll
  for (int j = 0; j < 4; ++j) {
    int e = (t + j * 256) * 4;
    float4 w = *(const float4*)(norm_w + e);
    ushort4 o = make_ushort4(f2bf(yv[j * 4 + 0] * scale * w.x), f2bf(yv[j * 4 + 1] * scale * w.y),
                             f2bf(yv[j * 4 + 2] * scale * w.z), f2bf(yv[j * 4 + 3] * scale * w.w));
    *(ushort4*)(orow + e) = o;
  }
}

extern "C" void kernel_launch(void* const* d_in, const int* in_sizes, int n_in,
                              void* d_out, int out_size, void* d_ws, size_t ws_size,
                              hipStream_t stream) {
  const float* u       = (const float*)d_in[0];
  const float* W_in    = (const float*)d_in[1];
  const float* conv_w  = (const float*)d_in[2];
  const float* conv_b  = (const float*)d_in[3];
  const float* dt_bias = (const float*)d_in[4];
  const float* A_log   = (const float*)d_in[5];
  const float* Dp      = (const float*)d_in[6];
  const float* norm_w  = (const float*)d_in[7];
  const float* W_out   = (const float*)d_in[8];
  float* out = (float*)d_out;

  char* ws = (char*)d_ws;
  size_t off = 0;
  auto alloc = [&](size_t bytes) { char* p = ws + off; off += (bytes + 255) & ~(size_t)255; return p; };
  unsigned short* ub   = (unsigned short*)alloc((size_t)NROWS * D_MODEL * 2);
  unsigned short* winb = (unsigned short*)alloc((size_t)D_IN_PROJ * D_MODEL * 2);
  unsigned short* zb   = (unsigned short*)alloc((size_t)NROWS * D_INNER * 2);
  unsigned short* xb   = (unsigned short*)alloc((size_t)NROWS * CONV_DIM * 2);
  unsigned short* xbcb = (unsigned short*)alloc((size_t)NROWS * CONV_DIM * 2);
  float* dtt  = (float*)alloc((size_t)BATCH * NHEADS * SEQ * 4);
  float* acum = (float*)alloc((size_t)BATCH * NHEADS * NCHUNK * CHUNK * 4);
  unsigned short* cwT = (unsigned short*)alloc((size_t)4 * CONV_DIM * 2);
  unsigned short* cbT = (unsigned short*)alloc((size_t)CONV_DIM * 2);
  unsigned short* whl = (unsigned short*)alloc((size_t)128 * D_MODEL * 2);
  float* PD = (float*)alloc((size_t)4 * BATCH * NHEADS * SEQ * 4);
  unsigned short* wob = ub;
  unsigned short* cbt = winb;
  unsigned short* psb = winb + (size_t)BATCH * NCHUNK * CHUNK * CHUNK + 1024;
  unsigned short* ulob = xbcb;
  unsigned short* yb = xb;
  float* states = (float*)d_out;

  if (off > ws_size) {
    k_sentinel<<<1, 64, 0, stream>>>(out);
    return;
  }

  k_prep<<<6673, 256, 0, stream>>>(u, ub, ulob, W_in, winb, whl, conv_w, conv_b, cwT, cbT);
  k_gemm8p<<<(NROWS / 256) * (D_INNER / 256), 512, 0, stream>>>(ub, winb, zb, NROWS, D_INNER, D_MODEL);
  k_gemm128<1><<<(NROWS / 128) * (CONV_DIM / 128), 256, 0, stream>>>(ub, winb + (size_t)D_INNER * D_MODEL, xb, NROWS, CONV_DIM, D_MODEL);
  k_dtm<<<256, 256, 0, stream>>>(ub, ulob, whl, PD);
  k_dtred<<<BATCH * NHEADS, 256, 0, stream>>>(PD, dt_bias, A_log, dtt, acum);
  k_conv_silu<<<(int)(((long)(NROWS / 4) * CG + 255) / 256), 256, 0, stream>>>(xb, cwT, cbT, xbcb);
  k_cbtt<<<BATCH * NCHUNK * 4, 256, 0, stream>>>(xbcb, cbt);
  k_states<<<BATCH * NCHUNK * NHEADS, 256, 0, stream>>>(xbcb, dtt, acum, states);
  k_scan<<<(BATCH * NHEADS * D_STATE * HEADDIM + 255) / 256, 256, 0, stream>>>(states, acum, psb);
  k_y<<<BATCH * NCHUNK * NHEADS, 256, 0, stream>>>(xbcb, dtt, acum, cbt, psb, Dp, yb);
  k_norm<<<NROWS, 256, 0, stream>>>(yb, zb, norm_w, yb);
  k_f32_to_bf16_v4<<<2048, 256, 0, stream>>>(W_out, wob, (long)D_MODEL * D_INNER / 4);
  k_gemm128<0><<<(NROWS / 128) * (D_MODEL / 128), 256, 0, stream>>>(yb, wob, out, NROWS, D_MODEL, D_INNER);
}